// Round 1
// baseline (22393.471 us; speedup 1.0000x reference)
//
#include <hip/hip_runtime.h>
#include <cstdint>
#include <cstddef>

// Problem constants
#define BB 64      // batch
#define SS 50      // src len
#define TT 50      // tgt len
#define TD 49      // decoder steps (T-1)
#define UU 1024    // hidden
#define EE 256     // embed
#define VT 16000   // tgt vocab
#define G3 3072    // 3*U

// ---------------------------------------------------------------------------
// Generic tiled SGEMM: C[M,N] = A[M,K] @ B[K,N] (+ bias[N]) (+ addend[M,N])
// A row-major with leading dim lda; optional rowmap gathers A rows (embedding).
// B row-major with leading dim == N. M%64==0, N%64==0, K%16==0 assumed.
// ---------------------------------------------------------------------------
#define BM 64
#define BN 64
#define BK 16

__global__ __launch_bounds__(256) void sgemm64(
    const float* __restrict__ A, const float* __restrict__ Bm,
    const float* __restrict__ bias, const float* __restrict__ addend,
    float* __restrict__ C, int M, int N, int K, int lda,
    const int* __restrict__ rowmap)
{
    __shared__ float As[BK][BM + 4];
    __shared__ float Bs[BK][BN + 4];
    const int tid = threadIdx.x;
    const int tx = tid & 15;   // output n group
    const int ty = tid >> 4;   // output m group
    const int n0 = blockIdx.x * BN;
    const int m0 = blockIdx.y * BM;

    const int a_k = tid & 15;   // k within tile for A loads
    const int a_m = tid >> 4;   // m (plus l*16)
    const int b_n = (tid & 15) * 4;
    const int b_k = tid >> 4;

    float acc[4][4] = {};
    for (int k0 = 0; k0 < K; k0 += BK) {
        #pragma unroll
        for (int l = 0; l < 4; ++l) {
            int m = a_m + l * 16;
            int gm = m0 + m;
            int row = rowmap ? rowmap[gm] : gm;
            As[a_k][m] = A[(size_t)row * lda + k0 + a_k];
        }
        const float4 bv = *(const float4*)(Bm + (size_t)(k0 + b_k) * N + n0 + b_n);
        Bs[b_k][b_n + 0] = bv.x; Bs[b_k][b_n + 1] = bv.y;
        Bs[b_k][b_n + 2] = bv.z; Bs[b_k][b_n + 3] = bv.w;
        __syncthreads();
        #pragma unroll
        for (int k = 0; k < BK; ++k) {
            float4 av  = *(const float4*)&As[k][ty * 4];
            float4 bv2 = *(const float4*)&Bs[k][tx * 4];
            float a_[4] = {av.x, av.y, av.z, av.w};
            float b_[4] = {bv2.x, bv2.y, bv2.z, bv2.w};
            #pragma unroll
            for (int i = 0; i < 4; ++i)
                #pragma unroll
                for (int j = 0; j < 4; ++j)
                    acc[i][j] += a_[i] * b_[j];
        }
        __syncthreads();
    }
    #pragma unroll
    for (int i = 0; i < 4; ++i) {
        int m = m0 + ty * 4 + i;
        #pragma unroll
        for (int j = 0; j < 4; ++j) {
            int n = n0 + tx * 4 + j;
            float v = acc[i][j];
            if (bias)   v += bias[n];
            if (addend) v += addend[(size_t)m * N + n];
            C[(size_t)m * N + n] = v;
        }
    }
}

// ---------------------------------------------------------------------------
// Init: build embedding rowmaps and zero the scalar output.
// rme[m] for m = s*B+b -> inp[b*S+s]; rmd[m] for m = t*B+b -> targ[b*T+t]
// ---------------------------------------------------------------------------
__global__ void init_kernel(const int* __restrict__ inp, const int* __restrict__ targ,
                            int* __restrict__ rme, int* __restrict__ rmd,
                            float* __restrict__ out)
{
    int i = blockIdx.x * 256 + threadIdx.x;
    if (i == 0) out[0] = 0.0f;
    if (i < SS * BB) { int s = i >> 6, b = i & 63; rme[i] = inp[b * SS + s]; }
    if (i < TD * BB) { int t = i >> 6, b = i & 63; rmd[i] = targ[b * TT + t]; }
}

__device__ __forceinline__ float sigm(float x) { return 1.0f / (1.0f + expf(-x)); }

// Encoder GRU pointwise: h_new = z*h + (1-z)*tanh(ih + r*hh)
__global__ __launch_bounds__(256) void gru_enc_pw(
    const float* __restrict__ gi, const float* __restrict__ gh,
    const float* __restrict__ hprev, float* __restrict__ hout)
{
    int i = blockIdx.x * 256 + threadIdx.x;        // 0 .. B*U-1
    int b = i >> 10, u = i & 1023;
    size_t base = (size_t)b * G3;
    float iz = gi[base + u], ir = gi[base + UU + u], ih = gi[base + 2 * UU + u];
    float hz = gh[base + u], hr = gh[base + UU + u], hh = gh[base + 2 * UU + u];
    float h = hprev[i];
    float z = sigm(iz + hz);
    float r = sigm(ir + hr);
    float hc = tanhf(ih + r * hh);
    hout[i] = z * h + (1.0f - z) * hc;
}

// Decoder GRU pointwise with h == 0: gh = dec_b[1] only; h_new = (1-z)*hcand
__global__ __launch_bounds__(256) void gru_dec_pw(
    const float* __restrict__ gi, const float* __restrict__ db1,
    float* __restrict__ hout)
{
    int i = blockIdx.x * 256 + threadIdx.x;
    int b = i >> 10, u = i & 1023;
    size_t base = (size_t)b * G3;
    float iz = gi[base + u], ir = gi[base + UU + u], ih = gi[base + 2 * UU + u];
    float z = sigm(iz + db1[u]);
    float r = sigm(ir + db1[UU + u]);
    float hc = tanhf(ih + r * db1[2 * UU + u]);
    hout[i] = (1.0f - z) * hc;
}

// ---------------------------------------------------------------------------
// Attention: per batch element b, score_s = V . tanh(q_b + keys[s,b,:]) + bV,
// softmax over s, ctx_b = sum_s attn_s * enc_out[s,b,:]
// ---------------------------------------------------------------------------
__global__ __launch_bounds__(256) void attn_kernel(
    const float* __restrict__ q, const float* __restrict__ keys,
    const float* __restrict__ enc_out, const float* __restrict__ Vw,
    const float* __restrict__ bV, float* __restrict__ ctx)
{
    int b = blockIdx.x;
    int tid = threadIdx.x;
    int wave = tid >> 6, lane = tid & 63;
    __shared__ float sc[64];
    __shared__ float attnw[64];

    const float* qp = q + (size_t)b * UU;
    for (int s = wave; s < SS; s += 4) {
        const float* kp = keys + ((size_t)s * BB + b) * UU;
        float p = 0.0f;
        for (int u = lane; u < UU; u += 64)
            p += Vw[u] * tanhf(qp[u] + kp[u]);
        for (int off = 32; off; off >>= 1) p += __shfl_down(p, off);
        if (lane == 0) sc[s] = p + bV[0];
    }
    __syncthreads();
    if (wave == 0) {
        float v = (lane < SS) ? sc[lane] : -INFINITY;
        float m = v;
        for (int off = 32; off; off >>= 1) m = fmaxf(m, __shfl_down(m, off));
        m = __shfl(m, 0);
        float e = (lane < SS) ? expf(v - m) : 0.0f;
        float ssum = e;
        for (int off = 32; off; off >>= 1) ssum += __shfl_down(ssum, off);
        ssum = __shfl(ssum, 0);
        if (lane < SS) attnw[lane] = e / ssum;
    }
    __syncthreads();
    for (int u = tid; u < UU; u += 256) {
        float acc = 0.0f;
        for (int s = 0; s < SS; ++s)
            acc += attnw[s] * enc_out[((size_t)s * BB + b) * UU + u];
        ctx[(size_t)b * UU + u] = acc;
    }
}

// ---------------------------------------------------------------------------
// Loss: one block per logits row. row r -> t = t0 + r/64, b = r%64.
// nll = logsumexp(logits) - logits[target]; out += nll*mask/B
// ---------------------------------------------------------------------------
__global__ __launch_bounds__(256) void loss_kernel(
    const float* __restrict__ logits, const int* __restrict__ targ,
    int t0, float* __restrict__ out)
{
    int r = blockIdx.x;
    int t = t0 + (r >> 6);
    int b = r & 63;
    const float* lp = logits + (size_t)r * VT;
    int tid = threadIdx.x;
    __shared__ float redm[4], reds[4];

    float m = -INFINITY;
    for (int v = tid; v < VT; v += 256) m = fmaxf(m, lp[v]);
    for (int off = 32; off; off >>= 1) m = fmaxf(m, __shfl_down(m, off));
    if ((tid & 63) == 0) redm[tid >> 6] = m;
    __syncthreads();
    float mm = fmaxf(fmaxf(redm[0], redm[1]), fmaxf(redm[2], redm[3]));

    float ssum = 0.0f;
    for (int v = tid; v < VT; v += 256) ssum += expf(lp[v] - mm);
    for (int off = 32; off; off >>= 1) ssum += __shfl_down(ssum, off);
    if ((tid & 63) == 0) reds[tid >> 6] = ssum;
    __syncthreads();
    if (tid == 0) {
        float tot = reds[0] + reds[1] + reds[2] + reds[3];
        int y = targ[b * TT + t + 1];
        float nll = mm + logf(tot) - lp[y];
        if (y != 0) atomicAdd(out, nll * (1.0f / (float)BB));
    }
}

// ---------------------------------------------------------------------------
extern "C" void kernel_launch(void* const* d_in, const int* in_sizes, int n_in,
                              void* d_out, int out_size, void* d_ws, size_t ws_size,
                              hipStream_t stream)
{
    (void)in_sizes; (void)n_in; (void)out_size; (void)ws_size;
    const int*   inp      = (const int*)  d_in[0];
    const int*   targ     = (const int*)  d_in[1];
    const float* enc_h0   = (const float*)d_in[2];
    const float* enc_emb  = (const float*)d_in[3];
    const float* enc_Wx   = (const float*)d_in[4];
    const float* enc_Wh   = (const float*)d_in[5];
    const float* enc_b    = (const float*)d_in[6];
    const float* W1       = (const float*)d_in[7];
    const float* b1       = (const float*)d_in[8];
    const float* W2       = (const float*)d_in[9];
    const float* b2       = (const float*)d_in[10];
    const float* Vw       = (const float*)d_in[11];
    const float* bV       = (const float*)d_in[12];
    const float* dec_emb  = (const float*)d_in[13];
    const float* dec_Wx   = (const float*)d_in[14];
    /* dec_Wh (d_in[15]) mathematically unused: decoder GRU gets h==0 */
    const float* dec_b    = (const float*)d_in[16];
    const float* fc_W     = (const float*)d_in[17];
    const float* fc_b     = (const float*)d_in[18];
    float* out = (float*)d_out;

    // workspace carve-up (16B aligned)
    char* p = (char*)d_ws;
    auto alloc = [&](size_t bytes) {
        char* r = (char*)(((uintptr_t)p + 15) & ~(uintptr_t)15);
        p = r + bytes;
        return r;
    };
    float* enc_gi  = (float*)alloc((size_t)SS * BB * G3 * 4);  // [S][B][3U]
    float* xemb_gi = (float*)alloc((size_t)TD * BB * G3 * 4);  // [T-1][B][3U]
    float* enc_out = (float*)alloc((size_t)SS * BB * UU * 4);  // [S][B][U]
    float* keys    = (float*)alloc((size_t)SS * BB * UU * 4);  // [S][B][U]
    float* H_all   = (float*)alloc((size_t)TD * BB * UU * 4);  // [T-1][B][U]
    float* ghb     = (float*)alloc((size_t)BB * G3 * 4);
    float* qb      = (float*)alloc((size_t)BB * UU * 4);
    float* ctxb    = (float*)alloc((size_t)BB * UU * 4);
    float* gib     = (float*)alloc((size_t)BB * G3 * 4);
    float* logits  = (float*)alloc((size_t)7 * BB * VT * 4);   // chunk of 7 steps
    int*   rme     = (int*)alloc((size_t)SS * BB * 4);
    int*   rmd     = (int*)alloc((size_t)TD * BB * 4);

    // init rowmaps + zero output
    init_kernel<<<13, 256, 0, stream>>>(inp, targ, rme, rmd, out);

    // encoder input-side gi for all steps: gathered A = enc_emb
    sgemm64<<<dim3(G3 / BN, (SS * BB) / BM), 256, 0, stream>>>(
        enc_emb, enc_Wx, enc_b, nullptr, enc_gi, SS * BB, G3, EE, EE, rme);
    // decoder embedding-side gi for all steps (includes dec_b[0])
    sgemm64<<<dim3(G3 / BN, (TD * BB) / BM), 256, 0, stream>>>(
        dec_emb, dec_Wx + (size_t)UU * G3, dec_b, nullptr, xemb_gi, TD * BB, G3, EE, EE, rmd);

    // encoder scan
    for (int t = 0; t < SS; ++t) {
        const float* hprev = t ? (enc_out + (size_t)(t - 1) * BB * UU) : enc_h0;
        sgemm64<<<dim3(G3 / BN, 1), 256, 0, stream>>>(
            hprev, enc_Wh, enc_b + G3, nullptr, ghb, BB, G3, UU, UU, nullptr);
        gru_enc_pw<<<(BB * UU) / 256, 256, 0, stream>>>(
            enc_gi + (size_t)t * BB * G3, ghb, hprev, enc_out + (size_t)t * BB * UU);
    }

    // keys = enc_out @ W2 + b2
    sgemm64<<<dim3(UU / BN, (SS * BB) / BM), 256, 0, stream>>>(
        enc_out, W2, b2, nullptr, keys, SS * BB, UU, UU, UU, nullptr);

    // decoder scan
    for (int t = 0; t < TD; ++t) {
        const float* dh = t ? (H_all + (size_t)(t - 1) * BB * UU)
                            : (enc_out + (size_t)(SS - 1) * BB * UU);
        sgemm64<<<dim3(UU / BN, 1), 256, 0, stream>>>(
            dh, W1, b1, nullptr, qb, BB, UU, UU, UU, nullptr);
        attn_kernel<<<BB, 256, 0, stream>>>(qb, keys, enc_out, Vw, bV, ctxb);
        sgemm64<<<dim3(G3 / BN, 1), 256, 0, stream>>>(
            ctxb, dec_Wx, nullptr, xemb_gi + (size_t)t * BB * G3, gib, BB, G3, UU, UU, nullptr);
        gru_dec_pw<<<(BB * UU) / 256, 256, 0, stream>>>(
            gib, dec_b + G3, H_all + (size_t)t * BB * UU);
    }

    // fc + loss in 7 chunks of 7 steps (448 rows each)
    for (int c = 0; c < 7; ++c) {
        const float* Arows = H_all + (size_t)c * 7 * BB * UU;
        sgemm64<<<dim3(VT / BN, (7 * BB) / BM), 256, 0, stream>>>(
            Arows, fc_W, fc_b, nullptr, logits, 7 * BB, VT, UU, UU, nullptr);
        loss_kernel<<<7 * BB, 256, 0, stream>>>(logits, targ, c * 7, out);
    }
}

// Round 2
// 8603.856 us; speedup vs baseline: 2.6027x; 2.6027x over previous
//
#include <hip/hip_runtime.h>
#include <cstdint>
#include <cstddef>

#define BB 64      // batch
#define SS 50      // src len
#define TT 50      // tgt len
#define TD 49      // decoder steps
#define UU 1024    // hidden
#define EE 256     // embed
#define VT 16000   // tgt vocab
#define G3 3072    // 3*U
#define MPAD 3200  // 50*64, padded row count (>= 49*64)

using short8 = __attribute__((ext_vector_type(8))) short;
using f32x4  = __attribute__((ext_vector_type(4))) float;

__device__ __forceinline__ short f2bf(float f) {
    uint32_t u = __float_as_uint(f);
    uint32_t r = (u + 0x7fffu + ((u >> 16) & 1u)) >> 16;
    return (short)r;
}
__device__ __forceinline__ float bf2f(short s) {
    return __uint_as_float(((uint32_t)(uint16_t)s) << 16);
}
__device__ __forceinline__ float sigm(float x) { return 1.0f / (1.0f + expf(-x)); }

typedef __attribute__((address_space(3))) void lds_vp;
typedef __attribute__((address_space(1))) void gl_vp;
__device__ __forceinline__ void gload16(void* lds, const void* g) {
    __builtin_amdgcn_global_load_lds((const gl_vp*)(uintptr_t)g,
                                     (lds_vp*)(uint32_t)(uintptr_t)lds,
                                     16, 0, 0);
}

// ---------------------------------------------------------------------------
// bf16 MFMA GEMM. A: bf16 [M][K] (lda), Bt: bf16 [N][K] (ldb). C = A@B^T' ...
// i.e. C[m][n] = sum_k A[m][k]*Bt[n][k]  (Bt is the transposed weight).
// C fp32 or bf16 (+bias fp32[N]) (+addend fp32/bf16 [gridM][N]).
// Grid: (N/BN, Mtiles). 256 threads = 4 waves (2x2 of WMxWN).
// ---------------------------------------------------------------------------
template<int BM, int BN, int WM, int WN, bool OUT_BF16, bool ADD_BF16>
__global__ __launch_bounds__(256) void gemm_bf16(
    const short* __restrict__ A, const short* __restrict__ Bt,
    const float* __restrict__ bias, const void* __restrict__ addend,
    void* __restrict__ C, int N, int K, int lda, int ldb)
{
    constexpr int BK = 32;
    __shared__ __attribute__((aligned(16))) short As[BM * BK];
    __shared__ __attribute__((aligned(16))) short Bs[BN * BK];

    const int tid  = threadIdx.x;
    const int wave = tid >> 6;
    const int lane = tid & 63;
    const int l15  = lane & 15;
    const int quad = lane >> 4;
    const int wm = wave >> 1, wn = wave & 1;
    const int n0 = blockIdx.x * BN;
    const int m0 = blockIdx.y * BM;

    f32x4 acc[WM / 16][WN / 16];
    #pragma unroll
    for (int i = 0; i < WM / 16; ++i)
        #pragma unroll
        for (int j = 0; j < WN / 16; ++j)
            acc[i][j] = (f32x4)0.0f;

    for (int k0 = 0; k0 < K; k0 += BK) {
        // stage A: BM x 32 bf16, 16B per lane
        #pragma unroll
        for (int it = 0; it < BM / 64; ++it) {
            int e = (it * 256 + tid) * 8;
            int row = e >> 5, col = e & 31;
            gload16(As + (it * 256 + wave * 64) * 8,
                    A + (size_t)(m0 + row) * lda + k0 + col);
        }
        #pragma unroll
        for (int it = 0; it < BN / 64; ++it) {
            int e = (it * 256 + tid) * 8;
            int row = e >> 5, col = e & 31;
            gload16(Bs + (it * 256 + wave * 64) * 8,
                    Bt + (size_t)(n0 + row) * ldb + k0 + col);
        }
        __syncthreads();
        short8 af[WM / 16], bfr[WN / 16];
        #pragma unroll
        for (int i = 0; i < WM / 16; ++i)
            af[i] = *(const short8*)(As + (wm * WM + i * 16 + l15) * BK + quad * 8);
        #pragma unroll
        for (int j = 0; j < WN / 16; ++j)
            bfr[j] = *(const short8*)(Bs + (wn * WN + j * 16 + l15) * BK + quad * 8);
        #pragma unroll
        for (int i = 0; i < WM / 16; ++i)
            #pragma unroll
            for (int j = 0; j < WN / 16; ++j)
                acc[i][j] = __builtin_amdgcn_mfma_f32_16x16x32_bf16(af[i], bfr[j], acc[i][j], 0, 0, 0);
        __syncthreads();
    }

    // epilogue: D[row=(lane>>4)*4+r][col=lane&15] per 16x16 tile
    #pragma unroll
    for (int i = 0; i < WM / 16; ++i) {
        #pragma unroll
        for (int j = 0; j < WN / 16; ++j) {
            int row = m0 + wm * WM + i * 16 + quad * 4;
            int col = n0 + wn * WN + j * 16 + l15;
            float bia = bias ? bias[col] : 0.0f;
            #pragma unroll
            for (int r = 0; r < 4; ++r) {
                size_t off = (size_t)(row + r) * N + col;
                float v = acc[i][j][r] + bia;
                if (addend) {
                    if (ADD_BF16) v += bf2f(((const short*)addend)[off]);
                    else          v += ((const float*)addend)[off];
                }
                if (OUT_BF16) ((short*)C)[off] = f2bf(v);
                else          ((float*)C)[off] = v;
            }
        }
    }
}

// ---------------------------------------------------------------------------
// Transpose fp32 [K][N] -> bf16 [N][K]. Grid (N/64, K/64), 256 thr.
// ---------------------------------------------------------------------------
__global__ __launch_bounds__(256) void transpose_bf(
    const float* __restrict__ in, short* __restrict__ out, int ldin, int ldout)
{
    __shared__ float tile[64][65];
    int n0 = blockIdx.x * 64, k0 = blockIdx.y * 64;
    int c = threadIdx.x & 63, rr = threadIdx.x >> 6;
    #pragma unroll 4
    for (int i = 0; i < 16; ++i) {
        int row = rr * 16 + i;
        tile[row][c] = in[(size_t)(k0 + row) * ldin + n0 + c];
    }
    __syncthreads();
    #pragma unroll 4
    for (int i = 0; i < 16; ++i) {
        int row = rr * 16 + i;
        out[(size_t)(n0 + row) * ldout + k0 + c] = f2bf(tile[c][row]);
    }
}

// ---------------------------------------------------------------------------
// Prep: gather embeddings to bf16 dense A, zero pads, zero output scalar.
// Grid 6464 blocks x 256.
// ---------------------------------------------------------------------------
__global__ __launch_bounds__(256) void prep_gather(
    const int* __restrict__ inp, const int* __restrict__ targ,
    const float* __restrict__ enc_emb, const float* __restrict__ dec_emb,
    short* __restrict__ Ae, short* __restrict__ Ad,
    short* __restrict__ H_bf, short* __restrict__ h0_bf, float* __restrict__ out)
{
    int blk = blockIdx.x, tid = threadIdx.x;
    if (blk < MPAD) {
        int s = blk >> 6, b = blk & 63;
        int row = inp[b * SS + s];
        Ae[(size_t)blk * EE + tid] = f2bf(enc_emb[(size_t)row * EE + tid]);
    } else if (blk < 2 * MPAD) {
        int m = blk - MPAD;
        if (m < TD * BB) {
            int t = m >> 6, b = m & 63;
            int row = targ[b * TT + t];
            Ad[(size_t)m * EE + tid] = f2bf(dec_emb[(size_t)row * EE + tid]);
        } else {
            Ad[(size_t)m * EE + tid] = 0;
        }
    } else {
        int r = blk - 2 * MPAD;  // 0..63
        for (int u = tid; u < UU; u += 256) {
            H_bf[(size_t)(TD * BB + r) * UU + u] = 0;
            h0_bf[(size_t)r * UU + u] = 0;
        }
        if (r == 0 && tid == 0) out[0] = 0.0f;
    }
}

// Encoder GRU pointwise (bf16 gi/h, fp32 gh)
__global__ __launch_bounds__(256) void gru_enc_pw(
    const short* __restrict__ gi, const float* __restrict__ gh,
    const short* __restrict__ hprev, short* __restrict__ hout)
{
    int i = blockIdx.x * 256 + threadIdx.x;   // B*U
    int b = i >> 10, u = i & 1023;
    size_t base = (size_t)b * G3;
    float iz = bf2f(gi[base + u]), ir = bf2f(gi[base + UU + u]), ih = bf2f(gi[base + 2 * UU + u]);
    float hz = gh[base + u], hr = gh[base + UU + u], hh = gh[base + 2 * UU + u];
    float h = bf2f(hprev[i]);
    float z = sigm(iz + hz);
    float r = sigm(ir + hr);
    float hc = tanhf(ih + r * hh);
    hout[i] = f2bf(z * h + (1.0f - z) * hc);
}

// Decoder GRU pointwise, h==0: gh side = dec_b[1] only
__global__ __launch_bounds__(256) void gru_dec_pw(
    const float* __restrict__ gi, const float* __restrict__ db1,
    short* __restrict__ hout)
{
    int i = blockIdx.x * 256 + threadIdx.x;
    int b = i >> 10, u = i & 1023;
    size_t base = (size_t)b * G3;
    float iz = gi[base + u], ir = gi[base + UU + u], ih = gi[base + 2 * UU + u];
    float z = sigm(iz + db1[u]);
    float r = sigm(ir + db1[UU + u]);
    float hc = tanhf(ih + r * db1[2 * UU + u]);
    hout[i] = f2bf((1.0f - z) * hc);
}

// Attention per batch element
__global__ __launch_bounds__(256) void attn_kernel(
    const float* __restrict__ q, const float* __restrict__ keys,
    const short* __restrict__ enc_out, const float* __restrict__ Vw,
    const float* __restrict__ bV, short* __restrict__ ctx)
{
    int b = blockIdx.x;
    int tid = threadIdx.x;
    int wave = tid >> 6, lane = tid & 63;
    __shared__ float sc[64];
    __shared__ float attnw[64];

    const float* qp = q + (size_t)b * UU;
    for (int s = wave; s < SS; s += 4) {
        const float* kp = keys + ((size_t)s * BB + b) * UU;
        float p = 0.0f;
        for (int u = lane; u < UU; u += 64)
            p += Vw[u] * tanhf(qp[u] + kp[u]);
        for (int off = 32; off; off >>= 1) p += __shfl_down(p, off);
        if (lane == 0) sc[s] = p + bV[0];
    }
    __syncthreads();
    if (wave == 0) {
        float v = (lane < SS) ? sc[lane] : -INFINITY;
        float m = v;
        for (int off = 32; off; off >>= 1) m = fmaxf(m, __shfl_down(m, off));
        m = __shfl(m, 0);
        float e = (lane < SS) ? expf(v - m) : 0.0f;
        float ssum = e;
        for (int off = 32; off; off >>= 1) ssum += __shfl_down(ssum, off);
        ssum = __shfl(ssum, 0);
        if (lane < SS) attnw[lane] = e / ssum;
    }
    __syncthreads();
    for (int u = tid; u < UU; u += 256) {
        float acc = 0.0f;
        for (int s = 0; s < SS; ++s)
            acc += attnw[s] * bf2f(enc_out[((size_t)s * BB + b) * UU + u]);
        ctx[(size_t)b * UU + u] = f2bf(acc);
    }
}

// Loss over one logits chunk. Grid = rows in chunk; skip pad rows (t>=TD).
__global__ __launch_bounds__(256) void loss_kernel(
    const float* __restrict__ logits, const int* __restrict__ targ,
    int rows0, float* __restrict__ out)
{
    int gr = rows0 + blockIdx.x;
    int t = gr >> 6;
    if (t >= TD) return;
    int b = gr & 63;
    const float* lp = logits + (size_t)blockIdx.x * VT;
    int tid = threadIdx.x;
    __shared__ float redm[4], reds[4];

    float m = -INFINITY;
    for (int v = tid; v < VT; v += 256) m = fmaxf(m, lp[v]);
    for (int off = 32; off; off >>= 1) m = fmaxf(m, __shfl_down(m, off));
    if ((tid & 63) == 0) redm[tid >> 6] = m;
    __syncthreads();
    float mm = fmaxf(fmaxf(redm[0], redm[1]), fmaxf(redm[2], redm[3]));

    float ssum = 0.0f;
    for (int v = tid; v < VT; v += 256) ssum += expf(lp[v] - mm);
    for (int off = 32; off; off >>= 1) ssum += __shfl_down(ssum, off);
    if ((tid & 63) == 0) reds[tid >> 6] = ssum;
    __syncthreads();
    if (tid == 0) {
        float tot = reds[0] + reds[1] + reds[2] + reds[3];
        int y = targ[b * TT + t + 1];
        float nll = mm + logf(tot) - lp[y];
        if (y != 0) atomicAdd(out, nll * (1.0f / (float)BB));
    }
}

// ---------------------------------------------------------------------------
extern "C" void kernel_launch(void* const* d_in, const int* in_sizes, int n_in,
                              void* d_out, int out_size, void* d_ws, size_t ws_size,
                              hipStream_t stream)
{
    (void)in_sizes; (void)n_in; (void)out_size; (void)ws_size;
    const int*   inp      = (const int*)  d_in[0];
    const int*   targ     = (const int*)  d_in[1];
    const float* enc_emb  = (const float*)d_in[3];
    const float* enc_Wx   = (const float*)d_in[4];
    const float* enc_Wh   = (const float*)d_in[5];
    const float* enc_b    = (const float*)d_in[6];
    const float* W1       = (const float*)d_in[7];
    const float* b1       = (const float*)d_in[8];
    const float* W2       = (const float*)d_in[9];
    const float* b2       = (const float*)d_in[10];
    const float* Vw       = (const float*)d_in[11];
    const float* bV       = (const float*)d_in[12];
    const float* dec_emb  = (const float*)d_in[13];
    const float* dec_Wx   = (const float*)d_in[14];
    /* dec_Wh (d_in[15]) mathematically unused: decoder GRU gets h==0 */
    const float* dec_b    = (const float*)d_in[16];
    const float* fc_W     = (const float*)d_in[17];
    const float* fc_b     = (const float*)d_in[18];
    float* out = (float*)d_out;

    char* p = (char*)d_ws;
    auto alloc = [&](size_t bytes) {
        char* r = (char*)(((uintptr_t)p + 255) & ~(uintptr_t)255);
        p = r + bytes;
        return r;
    };
    // bf16 transposed weights [N][K]
    short* encWxt  = (short*)alloc((size_t)G3 * EE * 2);
    short* encWht  = (short*)alloc((size_t)G3 * UU * 2);
    short* W1t     = (short*)alloc((size_t)UU * UU * 2);
    short* W2t     = (short*)alloc((size_t)UU * UU * 2);
    short* dWxt_c  = (short*)alloc((size_t)G3 * UU * 2);
    short* dWxt_e  = (short*)alloc((size_t)G3 * EE * 2);
    short* fcWt    = (short*)alloc((size_t)VT * UU * 2);
    // bf16 dense gathered embeddings
    short* Ae      = (short*)alloc((size_t)MPAD * EE * 2);
    short* Ad      = (short*)alloc((size_t)MPAD * EE * 2);
    // activations
    short* enc_gi  = (short*)alloc((size_t)MPAD * G3 * 2);   // bf16 [S*B][3U]
    short* xemb_gi = (short*)alloc((size_t)MPAD * G3 * 2);   // bf16
    short* enc_out = (short*)alloc((size_t)MPAD * UU * 2);   // bf16 h per step
    float* keys    = (float*)alloc((size_t)MPAD * UU * 4);   // fp32
    short* H_bf    = (short*)alloc((size_t)MPAD * UU * 2);   // decoder h bf16
    short* h0_bf   = (short*)alloc((size_t)BB * UU * 2);
    float* ghb     = (float*)alloc((size_t)BB * G3 * 4);
    float* qb      = (float*)alloc((size_t)BB * UU * 4);
    short* ctx_bf  = (short*)alloc((size_t)BB * UU * 2);
    float* gib     = (float*)alloc((size_t)BB * G3 * 4);
    float* logits  = (float*)alloc((size_t)256 * VT * 4);

    // --- one-time prep (parallel) ---
    transpose_bf<<<dim3(G3/64, EE/64), 256, 0, stream>>>(enc_Wx, encWxt, G3, EE);
    transpose_bf<<<dim3(G3/64, UU/64), 256, 0, stream>>>(enc_Wh, encWht, G3, UU);
    transpose_bf<<<dim3(UU/64, UU/64), 256, 0, stream>>>(W1, W1t, UU, UU);
    transpose_bf<<<dim3(UU/64, UU/64), 256, 0, stream>>>(W2, W2t, UU, UU);
    transpose_bf<<<dim3(G3/64, UU/64), 256, 0, stream>>>(dec_Wx, dWxt_c, G3, UU);
    transpose_bf<<<dim3(G3/64, EE/64), 256, 0, stream>>>(dec_Wx + (size_t)UU * G3, dWxt_e, G3, EE);
    transpose_bf<<<dim3(VT/64, UU/64), 256, 0, stream>>>(fc_W, fcWt, VT, UU);
    prep_gather<<<2 * MPAD + 64, 256, 0, stream>>>(inp, targ, enc_emb, dec_emb,
                                                   Ae, Ad, H_bf, h0_bf, out);

    // enc_gi = gather(enc_emb) @ enc_Wx + enc_b[0]   (bf16 out)
    gemm_bf16<128,128,64,64,true,false><<<dim3(G3/128, MPAD/128), 256, 0, stream>>>(
        Ae, encWxt, enc_b, nullptr, enc_gi, G3, EE, EE, EE);
    // xemb_gi = gather(dec_emb) @ dec_Wx[emb] + dec_b[0]   (bf16 out)
    gemm_bf16<128,128,64,64,true,false><<<dim3(G3/128, MPAD/128), 256, 0, stream>>>(
        Ad, dWxt_e, dec_b, nullptr, xemb_gi, G3, EE, EE, EE);

    // --- encoder scan ---
    for (int t = 0; t < SS; ++t) {
        const short* hprev = t ? (enc_out + (size_t)(t - 1) * BB * UU) : h0_bf;
        gemm_bf16<64,64,32,32,false,false><<<dim3(G3/64, 1), 256, 0, stream>>>(
            hprev, encWht, enc_b + G3, nullptr, ghb, G3, UU, UU, UU);
        gru_enc_pw<<<(BB * UU) / 256, 256, 0, stream>>>(
            enc_gi + (size_t)t * BB * G3, ghb, hprev, enc_out + (size_t)t * BB * UU);
    }

    // keys = enc_out @ W2 + b2  (fp32 out)
    gemm_bf16<128,128,64,64,false,false><<<dim3(UU/128, MPAD/128), 256, 0, stream>>>(
        enc_out, W2t, b2, nullptr, keys, UU, UU, UU, UU);

    // --- decoder scan ---
    for (int t = 0; t < TD; ++t) {
        const short* dh = t ? (H_bf + (size_t)(t - 1) * BB * UU)
                            : (enc_out + (size_t)(SS - 1) * BB * UU);
        gemm_bf16<64,64,32,32,false,false><<<dim3(UU/64, 1), 256, 0, stream>>>(
            dh, W1t, b1, nullptr, qb, UU, UU, UU, UU);
        attn_kernel<<<BB, 256, 0, stream>>>(qb, keys, enc_out, Vw, bV, ctx_bf);
        gemm_bf16<64,64,32,32,false,true><<<dim3(G3/64, 1), 256, 0, stream>>>(
            ctx_bf, dWxt_c, nullptr, xemb_gi + (size_t)t * BB * G3, gib, G3, UU, UU, UU);
        gru_dec_pw<<<(BB * UU) / 256, 256, 0, stream>>>(
            gib, dec_b + G3, H_bf + (size_t)t * BB * UU);
    }

    // --- fc + loss, chunks of 256 rows ---
    for (int rows0 = 0; rows0 < MPAD; rows0 += 256) {
        int rows = MPAD - rows0; if (rows > 256) rows = 256;
        gemm_bf16<128,128,64,64,false,false><<<dim3(VT/128, rows/128), 256, 0, stream>>>(
            H_bf + (size_t)rows0 * UU, fcWt, fc_b, nullptr, logits, VT, UU, UU, UU);
        loss_kernel<<<rows, 256, 0, stream>>>(logits, targ, rows0, out);
    }
}

// Round 3
// 5828.394 us; speedup vs baseline: 3.8421x; 1.4762x over previous
//
#include <hip/hip_runtime.h>
#include <hip/hip_cooperative_groups.h>
#include <cstdint>
#include <cstddef>

namespace cg = cooperative_groups;

#define BB 64      // batch
#define SS 50      // src len
#define TT 50      // tgt len
#define TD 49      // decoder steps
#define UU 1024    // hidden
#define EE 256     // embed
#define VT 16000   // tgt vocab
#define G3 3072    // 3*U
#define MPAD 3200  // 50*64 padded row count

using short8 = __attribute__((ext_vector_type(8))) short;
using short4v = __attribute__((ext_vector_type(4))) short;
using f32x4  = __attribute__((ext_vector_type(4))) float;

__device__ __forceinline__ short f2bf(float f) {
    uint32_t u = __float_as_uint(f);
    uint32_t r = (u + 0x7fffu + ((u >> 16) & 1u)) >> 16;
    return (short)r;
}
__device__ __forceinline__ float bf2f(short s) {
    return __uint_as_float(((uint32_t)(uint16_t)s) << 16);
}
__device__ __forceinline__ float sigm(float x) { return 1.0f / (1.0f + __expf(-x)); }
__device__ __forceinline__ float ftanh(float x) {
    float xc = fminf(fmaxf(x, -8.0f), 8.0f);
    float e = __expf(2.0f * xc);
    return (e - 1.0f) / (e + 1.0f);
}

typedef __attribute__((address_space(3))) void lds_vp;
typedef __attribute__((address_space(1))) void gl_vp;
__device__ __forceinline__ void gload16(void* lds, const void* g) {
    __builtin_amdgcn_global_load_lds((const gl_vp*)(uintptr_t)g,
                                     (lds_vp*)(uint32_t)(uintptr_t)lds,
                                     16, 0, 0);
}

// ---------------------------------------------------------------------------
// bf16 MFMA GEMM (parallel phases): C[m][n] = sum_k A[m][k]*Bt[n][k] (+bias)
// ---------------------------------------------------------------------------
template<int BM, int BN, int WM, int WN, bool OUT_BF16>
__global__ __launch_bounds__(256) void gemm_bf16(
    const short* __restrict__ A, const short* __restrict__ Bt,
    const float* __restrict__ bias, void* __restrict__ C, int N, int K,
    int lda, int ldb)
{
    constexpr int BK = 32;
    __shared__ __attribute__((aligned(16))) short As[BM * BK];
    __shared__ __attribute__((aligned(16))) short Bs[BN * BK];

    const int tid  = threadIdx.x;
    const int wave = tid >> 6;
    const int lane = tid & 63;
    const int l15  = lane & 15;
    const int quad = lane >> 4;
    const int wm = wave >> 1, wn = wave & 1;
    const int n0 = blockIdx.x * BN;
    const int m0 = blockIdx.y * BM;

    f32x4 acc[WM / 16][WN / 16];
    #pragma unroll
    for (int i = 0; i < WM / 16; ++i)
        #pragma unroll
        for (int j = 0; j < WN / 16; ++j)
            acc[i][j] = (f32x4)0.0f;

    for (int k0 = 0; k0 < K; k0 += BK) {
        #pragma unroll
        for (int it = 0; it < BM / 64; ++it) {
            int e = (it * 256 + tid) * 8;
            int row = e >> 5, col = e & 31;
            gload16(As + (it * 256 + wave * 64) * 8,
                    A + (size_t)(m0 + row) * lda + k0 + col);
        }
        #pragma unroll
        for (int it = 0; it < BN / 64; ++it) {
            int e = (it * 256 + tid) * 8;
            int row = e >> 5, col = e & 31;
            gload16(Bs + (it * 256 + wave * 64) * 8,
                    Bt + (size_t)(n0 + row) * ldb + k0 + col);
        }
        __syncthreads();
        short8 af[WM / 16], bfr[WN / 16];
        #pragma unroll
        for (int i = 0; i < WM / 16; ++i)
            af[i] = *(const short8*)(As + (wm * WM + i * 16 + l15) * BK + quad * 8);
        #pragma unroll
        for (int j = 0; j < WN / 16; ++j)
            bfr[j] = *(const short8*)(Bs + (wn * WN + j * 16 + l15) * BK + quad * 8);
        #pragma unroll
        for (int i = 0; i < WM / 16; ++i)
            #pragma unroll
            for (int j = 0; j < WN / 16; ++j)
                acc[i][j] = __builtin_amdgcn_mfma_f32_16x16x32_bf16(af[i], bfr[j], acc[i][j], 0, 0, 0);
        __syncthreads();
    }

    #pragma unroll
    for (int i = 0; i < WM / 16; ++i) {
        #pragma unroll
        for (int j = 0; j < WN / 16; ++j) {
            int row = m0 + wm * WM + i * 16 + quad * 4;
            int col = n0 + wn * WN + j * 16 + l15;
            float bia = bias ? bias[col] : 0.0f;
            #pragma unroll
            for (int r = 0; r < 4; ++r) {
                size_t off = (size_t)(row + r) * N + col;
                float v = acc[i][j][r] + bia;
                if (OUT_BF16) ((short*)C)[off] = f2bf(v);
                else          ((float*)C)[off] = v;
            }
        }
    }
}

// ---------------------------------------------------------------------------
// Transpose fp32 [K][N] -> bf16 [N][K]
// ---------------------------------------------------------------------------
__global__ __launch_bounds__(256) void transpose_bf(
    const float* __restrict__ in, short* __restrict__ out, int ldin, int ldout)
{
    __shared__ float tile[64][65];
    int n0 = blockIdx.x * 64, k0 = blockIdx.y * 64;
    int c = threadIdx.x & 63, rr = threadIdx.x >> 6;
    #pragma unroll 4
    for (int i = 0; i < 16; ++i) {
        int row = rr * 16 + i;
        tile[row][c] = in[(size_t)(k0 + row) * ldin + n0 + c];
    }
    __syncthreads();
    #pragma unroll 4
    for (int i = 0; i < 16; ++i) {
        int row = rr * 16 + i;
        out[(size_t)(n0 + row) * ldout + k0 + c] = f2bf(tile[c][row]);
    }
}

// ---------------------------------------------------------------------------
// Prep: gather embeddings to bf16, convert h0, zero pads, zero output.
// ---------------------------------------------------------------------------
__global__ __launch_bounds__(256) void prep_gather(
    const int* __restrict__ inp, const int* __restrict__ targ,
    const float* __restrict__ enc_emb, const float* __restrict__ dec_emb,
    const float* __restrict__ enc_h0,
    short* __restrict__ Ae, short* __restrict__ Ad,
    short* __restrict__ H_bf, short* __restrict__ h0_bf, float* __restrict__ out)
{
    int blk = blockIdx.x, tid = threadIdx.x;
    if (blk < MPAD) {
        int s = blk >> 6, b = blk & 63;
        int row = inp[b * SS + s];
        Ae[(size_t)blk * EE + tid] = f2bf(enc_emb[(size_t)row * EE + tid]);
    } else if (blk < 2 * MPAD) {
        int m = blk - MPAD;
        if (m < TD * BB) {
            int t = m >> 6, b = m & 63;
            int row = targ[b * TT + t];
            Ad[(size_t)m * EE + tid] = f2bf(dec_emb[(size_t)row * EE + tid]);
        } else {
            Ad[(size_t)m * EE + tid] = 0;
        }
    } else {
        int r = blk - 2 * MPAD;  // 0..63
        for (int u = tid; u < UU; u += 256) {
            H_bf[(size_t)(TD * BB + r) * UU + u] = 0;               // fc pad rows
            h0_bf[(size_t)r * UU + u] = f2bf(enc_h0[(size_t)r * UU + u]);
        }
        if (r == 0 && tid == 0) out[0] = 0.0f;
    }
}

// ---------------------------------------------------------------------------
// Encoder persistent scan. Grid 64 x 256. Block j owns u-slice [j*16,(j+1)*16).
// Per step: gh = h_prev @ Wh (3 gates for the slice, direct-to-VGPR MFMA),
// fused GRU pointwise, one grid sync. No LDS, no __syncthreads.
// ---------------------------------------------------------------------------
__global__ __launch_bounds__(256, 1) void enc_scan(
    const short* __restrict__ h0, const short* __restrict__ Wht,
    const short* __restrict__ gi, const float* __restrict__ bias2,
    short* __restrict__ eout)
{
    cg::grid_group grid = cg::this_grid();
    const int j    = blockIdx.x;
    const int tid  = threadIdx.x;
    const int wave = tid >> 6;
    const int lane = tid & 63;
    const int l15  = lane & 15;
    const int quad = lane >> 4;
    const int u    = j * 16 + l15;

    const short* Brow0 = Wht + ((size_t)(0 * UU + u)) * UU + quad * 8;
    const short* Brow1 = Wht + ((size_t)(1 * UU + u)) * UU + quad * 8;
    const short* Brow2 = Wht + ((size_t)(2 * UU + u)) * UU + quad * 8;
    const float bz = bias2[u], br = bias2[UU + u], bh = bias2[2 * UU + u];

    for (int t = 0; t < SS; ++t) {
        const short* A = t ? eout + (size_t)(t - 1) * BB * UU : h0;
        const short* Arow = A + (size_t)(wave * 16 + l15) * UU + quad * 8;
        f32x4 a0 = (f32x4)0.0f, a1 = (f32x4)0.0f, a2 = (f32x4)0.0f;
        #pragma unroll 8
        for (int i = 0; i < 32; ++i) {
            short8 af = *(const short8*)(Arow + i * 32);
            a0 = __builtin_amdgcn_mfma_f32_16x16x32_bf16(af, *(const short8*)(Brow0 + i * 32), a0, 0, 0, 0);
            a1 = __builtin_amdgcn_mfma_f32_16x16x32_bf16(af, *(const short8*)(Brow1 + i * 32), a1, 0, 0, 0);
            a2 = __builtin_amdgcn_mfma_f32_16x16x32_bf16(af, *(const short8*)(Brow2 + i * 32), a2, 0, 0, 0);
        }
        const short* git = gi + (size_t)t * BB * G3;
        #pragma unroll
        for (int r = 0; r < 4; ++r) {
            int b = wave * 16 + quad * 4 + r;
            const short* gb = git + (size_t)b * G3;
            float iz = bf2f(gb[u]), ir = bf2f(gb[UU + u]), ih = bf2f(gb[2 * UU + u]);
            float h = bf2f(A[(size_t)b * UU + u]);
            float z  = sigm(iz + a0[r] + bz);
            float rr = sigm(ir + a1[r] + br);
            float hc = ftanh(ih + rr * (a2[r] + bh));
            eout[(size_t)t * BB * UU + (size_t)b * UU + u] = f2bf(z * h + (1.0f - z) * hc);
        }
        grid.sync();
    }
}

// ---------------------------------------------------------------------------
// Decoder persistent scan. Grid 64 x 256. Per step 3 phases / 3 grid syncs:
//  P1: q = dh @ W1 + b1 (block j: 16-col slice)
//  P2: attention (block = batch b): scores, softmax, ctx
//  P3: gi = ctx @ dWx_c + xemb_gi; GRU(h=0) pointwise -> H[t]
// ---------------------------------------------------------------------------
__global__ __launch_bounds__(256, 1) void dec_scan(
    const short* __restrict__ eout, const short* __restrict__ W1t,
    const float* __restrict__ b1, const short* __restrict__ keysb,
    const float* __restrict__ Vw, const float* __restrict__ bV,
    const short* __restrict__ dWxt, const short* __restrict__ xg,
    const float* __restrict__ db1, float* __restrict__ qb,
    short* __restrict__ ctxb, short* __restrict__ Hbf)
{
    cg::grid_group grid = cg::this_grid();
    const int j    = blockIdx.x;
    const int tid  = threadIdx.x;
    const int wave = tid >> 6;
    const int lane = tid & 63;
    const int l15  = lane & 15;
    const int quad = lane >> 4;
    const int u    = j * 16 + l15;

    __shared__ float sc[64];
    __shared__ float attnw[64];

    const short* BrowQ = W1t + (size_t)u * UU + quad * 8;
    const short* BrowC0 = dWxt + ((size_t)(0 * UU + u)) * UU + quad * 8;
    const short* BrowC1 = dWxt + ((size_t)(1 * UU + u)) * UU + quad * 8;
    const short* BrowC2 = dWxt + ((size_t)(2 * UU + u)) * UU + quad * 8;
    const float b1v = b1[u];
    const float dz = db1[u], dr = db1[UU + u], dhh = db1[2 * UU + u];
    const float bV0 = bV[0];

    float Vl[16];
    #pragma unroll
    for (int e = 0; e < 16; e += 4)
        *(float4*)&Vl[e] = *(const float4*)(Vw + lane * 16 + e);

    for (int t = 0; t < TD; ++t) {
        const short* dh = t ? Hbf + (size_t)(t - 1) * BB * UU
                            : eout + (size_t)(SS - 1) * BB * UU;
        // ---- P1: q slice ----
        {
            const short* Arow = dh + (size_t)(wave * 16 + l15) * UU + quad * 8;
            f32x4 aq = (f32x4)0.0f;
            #pragma unroll 8
            for (int i = 0; i < 32; ++i) {
                short8 af = *(const short8*)(Arow + i * 32);
                aq = __builtin_amdgcn_mfma_f32_16x16x32_bf16(af, *(const short8*)(BrowQ + i * 32), aq, 0, 0, 0);
            }
            #pragma unroll
            for (int r = 0; r < 4; ++r)
                qb[(size_t)(wave * 16 + quad * 4 + r) * UU + u] = aq[r] + b1v;
        }
        grid.sync();
        // ---- P2: attention, block = batch b ----
        {
            const int b = j;
            float ql[16];
            #pragma unroll
            for (int e = 0; e < 16; e += 4)
                *(float4*)&ql[e] = *(const float4*)(qb + (size_t)b * UU + lane * 16 + e);
            for (int s = wave; s < SS; s += 4) {
                const short* kp = keysb + ((size_t)s * BB + b) * UU + lane * 16;
                short8 k0 = *(const short8*)kp;
                short8 k1 = *(const short8*)(kp + 8);
                float p = 0.0f;
                #pragma unroll
                for (int e = 0; e < 8; ++e) p += Vl[e] * ftanh(ql[e] + bf2f(k0[e]));
                #pragma unroll
                for (int e = 0; e < 8; ++e) p += Vl[8 + e] * ftanh(ql[8 + e] + bf2f(k1[e]));
                #pragma unroll
                for (int off = 32; off; off >>= 1) p += __shfl_down(p, off);
                if (lane == 0) sc[s] = p + bV0;
            }
            __syncthreads();
            if (wave == 0) {
                float v = (lane < SS) ? sc[lane] : -1e30f;
                float m = v;
                #pragma unroll
                for (int off = 32; off; off >>= 1) m = fmaxf(m, __shfl_down(m, off));
                m = __shfl(m, 0);
                float e = (lane < SS) ? __expf(v - m) : 0.0f;
                float ss = e;
                #pragma unroll
                for (int off = 32; off; off >>= 1) ss += __shfl_down(ss, off);
                ss = __shfl(ss, 0);
                if (lane < SS) attnw[lane] = e / ss;
            }
            __syncthreads();
            float fa0 = 0, fa1 = 0, fa2 = 0, fa3 = 0;
            for (int s = 0; s < SS; ++s) {
                float w = attnw[s];
                short4v ev = *(const short4v*)(eout + ((size_t)s * BB + b) * UU + tid * 4);
                fa0 += w * bf2f(ev[0]); fa1 += w * bf2f(ev[1]);
                fa2 += w * bf2f(ev[2]); fa3 += w * bf2f(ev[3]);
            }
            short4v cv;
            cv[0] = f2bf(fa0); cv[1] = f2bf(fa1); cv[2] = f2bf(fa2); cv[3] = f2bf(fa3);
            *(short4v*)(ctxb + (size_t)b * UU + tid * 4) = cv;
        }
        grid.sync();
        // ---- P3: gi slice + GRU(h=0) pointwise ----
        {
            const short* Arow = ctxb + (size_t)(wave * 16 + l15) * UU + quad * 8;
            f32x4 a0 = (f32x4)0.0f, a1 = (f32x4)0.0f, a2 = (f32x4)0.0f;
            #pragma unroll 8
            for (int i = 0; i < 32; ++i) {
                short8 af = *(const short8*)(Arow + i * 32);
                a0 = __builtin_amdgcn_mfma_f32_16x16x32_bf16(af, *(const short8*)(BrowC0 + i * 32), a0, 0, 0, 0);
                a1 = __builtin_amdgcn_mfma_f32_16x16x32_bf16(af, *(const short8*)(BrowC1 + i * 32), a1, 0, 0, 0);
                a2 = __builtin_amdgcn_mfma_f32_16x16x32_bf16(af, *(const short8*)(BrowC2 + i * 32), a2, 0, 0, 0);
            }
            const short* xgt = xg + (size_t)t * BB * G3;
            #pragma unroll
            for (int r = 0; r < 4; ++r) {
                int b = wave * 16 + quad * 4 + r;
                const short* xb = xgt + (size_t)b * G3;
                float g0 = a0[r] + bf2f(xb[u]);
                float g1 = a1[r] + bf2f(xb[UU + u]);
                float g2 = a2[r] + bf2f(xb[2 * UU + u]);
                float z  = sigm(g0 + dz);
                float rr = sigm(g1 + dr);
                float hc = ftanh(g2 + rr * dhh);
                Hbf[(size_t)t * BB * UU + (size_t)b * UU + u] = f2bf((1.0f - z) * hc);
            }
        }
        grid.sync();
    }
}

// ---------------------------------------------------------------------------
// Loss over one logits chunk.
// ---------------------------------------------------------------------------
__global__ __launch_bounds__(256) void loss_kernel(
    const float* __restrict__ logits, const int* __restrict__ targ,
    int rows0, float* __restrict__ out)
{
    int gr = rows0 + blockIdx.x;
    int t = gr >> 6;
    if (t >= TD) return;
    int b = gr & 63;
    const float* lp = logits + (size_t)blockIdx.x * VT;
    int tid = threadIdx.x;
    __shared__ float redm[4], reds[4];

    float m = -INFINITY;
    for (int v = tid; v < VT; v += 256) m = fmaxf(m, lp[v]);
    #pragma unroll
    for (int off = 32; off; off >>= 1) m = fmaxf(m, __shfl_down(m, off));
    if ((tid & 63) == 0) redm[tid >> 6] = m;
    __syncthreads();
    float mm = fmaxf(fmaxf(redm[0], redm[1]), fmaxf(redm[2], redm[3]));

    float ssum = 0.0f;
    for (int v = tid; v < VT; v += 256) ssum += expf(lp[v] - mm);
    #pragma unroll
    for (int off = 32; off; off >>= 1) ssum += __shfl_down(ssum, off);
    if ((tid & 63) == 0) reds[tid >> 6] = ssum;
    __syncthreads();
    if (tid == 0) {
        float tot = reds[0] + reds[1] + reds[2] + reds[3];
        int y = targ[b * TT + t + 1];
        float nll = mm + logf(tot) - lp[y];
        if (y != 0) atomicAdd(out, nll * (1.0f / (float)BB));
    }
}

// ---------------------------------------------------------------------------
extern "C" void kernel_launch(void* const* d_in, const int* in_sizes, int n_in,
                              void* d_out, int out_size, void* d_ws, size_t ws_size,
                              hipStream_t stream)
{
    (void)in_sizes; (void)n_in; (void)out_size; (void)ws_size;
    const int*   inp      = (const int*)  d_in[0];
    const int*   targ     = (const int*)  d_in[1];
    const float* enc_h0   = (const float*)d_in[2];
    const float* enc_emb  = (const float*)d_in[3];
    const float* enc_Wx   = (const float*)d_in[4];
    const float* enc_Wh   = (const float*)d_in[5];
    const float* enc_b    = (const float*)d_in[6];
    const float* W1       = (const float*)d_in[7];
    const float* b1       = (const float*)d_in[8];
    const float* W2       = (const float*)d_in[9];
    const float* b2       = (const float*)d_in[10];
    const float* Vw       = (const float*)d_in[11];
    const float* bV       = (const float*)d_in[12];
    const float* dec_emb  = (const float*)d_in[13];
    const float* dec_Wx   = (const float*)d_in[14];
    /* dec_Wh (d_in[15]) mathematically unused: decoder GRU gets h==0 */
    const float* dec_b    = (const float*)d_in[16];
    const float* fc_W     = (const float*)d_in[17];
    const float* fc_b     = (const float*)d_in[18];
    float* out = (float*)d_out;

    char* p = (char*)d_ws;
    auto alloc = [&](size_t bytes) {
        char* r = (char*)(((uintptr_t)p + 255) & ~(uintptr_t)255);
        p = r + bytes;
        return r;
    };
    short* encWxt  = (short*)alloc((size_t)G3 * EE * 2);
    short* encWht  = (short*)alloc((size_t)G3 * UU * 2);
    short* W1t     = (short*)alloc((size_t)UU * UU * 2);
    short* W2t     = (short*)alloc((size_t)UU * UU * 2);
    short* dWxt_c  = (short*)alloc((size_t)G3 * UU * 2);
    short* dWxt_e  = (short*)alloc((size_t)G3 * EE * 2);
    short* fcWt    = (short*)alloc((size_t)VT * UU * 2);
    short* Ae      = (short*)alloc((size_t)MPAD * EE * 2);
    short* Ad      = (short*)alloc((size_t)MPAD * EE * 2);
    short* enc_gi  = (short*)alloc((size_t)MPAD * G3 * 2);
    short* xemb_gi = (short*)alloc((size_t)MPAD * G3 * 2);
    short* enc_out = (short*)alloc((size_t)MPAD * UU * 2);
    short* keysb   = (short*)alloc((size_t)MPAD * UU * 2);
    short* H_bf    = (short*)alloc((size_t)MPAD * UU * 2);
    short* h0_bf   = (short*)alloc((size_t)BB * UU * 2);
    float* qb      = (float*)alloc((size_t)BB * UU * 4);
    short* ctx_bf  = (short*)alloc((size_t)BB * UU * 2);
    float* logits  = (float*)alloc((size_t)256 * VT * 4);

    // --- one-time prep (parallel) ---
    transpose_bf<<<dim3(G3/64, EE/64), 256, 0, stream>>>(enc_Wx, encWxt, G3, EE);
    transpose_bf<<<dim3(G3/64, UU/64), 256, 0, stream>>>(enc_Wh, encWht, G3, UU);
    transpose_bf<<<dim3(UU/64, UU/64), 256, 0, stream>>>(W1, W1t, UU, UU);
    transpose_bf<<<dim3(UU/64, UU/64), 256, 0, stream>>>(W2, W2t, UU, UU);
    transpose_bf<<<dim3(G3/64, UU/64), 256, 0, stream>>>(dec_Wx, dWxt_c, G3, UU);
    transpose_bf<<<dim3(G3/64, EE/64), 256, 0, stream>>>(dec_Wx + (size_t)UU * G3, dWxt_e, G3, EE);
    transpose_bf<<<dim3(VT/64, UU/64), 256, 0, stream>>>(fc_W, fcWt, VT, UU);
    prep_gather<<<2 * MPAD + 64, 256, 0, stream>>>(inp, targ, enc_emb, dec_emb, enc_h0,
                                                   Ae, Ad, H_bf, h0_bf, out);

    gemm_bf16<128,128,64,64,true><<<dim3(G3/128, MPAD/128), 256, 0, stream>>>(
        Ae, encWxt, enc_b, enc_gi, G3, EE, EE, EE);
    gemm_bf16<128,128,64,64,true><<<dim3(G3/128, MPAD/128), 256, 0, stream>>>(
        Ad, dWxt_e, dec_b, xemb_gi, G3, EE, EE, EE);

    // --- encoder persistent scan (cooperative) ---
    {
        const short* a0 = h0_bf; const short* a1 = encWht; const short* a2 = enc_gi;
        const float* a3 = enc_b + G3; short* a4 = enc_out;
        void* args[] = {&a0, &a1, &a2, &a3, &a4};
        hipLaunchCooperativeKernel((void*)enc_scan, dim3(64), dim3(256), args, 0, stream);
    }

    // keys = enc_out @ W2 + b2  (bf16)
    gemm_bf16<128,128,64,64,true><<<dim3(UU/128, MPAD/128), 256, 0, stream>>>(
        enc_out, W2t, b2, keysb, UU, UU, UU, UU);

    // --- decoder persistent scan (cooperative) ---
    {
        const short* a0 = enc_out; const short* a1 = W1t; const float* a2 = b1;
        const short* a3 = keysb; const float* a4 = Vw; const float* a5 = bV;
        const short* a6 = dWxt_c; const short* a7 = xemb_gi; const float* a8 = dec_b + G3;
        float* a9 = qb; short* a10 = ctx_bf; short* a11 = H_bf;
        void* args[] = {&a0, &a1, &a2, &a3, &a4, &a5, &a6, &a7, &a8, &a9, &a10, &a11};
        hipLaunchCooperativeKernel((void*)dec_scan, dim3(64), dim3(256), args, 0, stream);
    }

    // --- fc + loss, chunks of 256 rows ---
    for (int rows0 = 0; rows0 < MPAD; rows0 += 256) {
        int rows = MPAD - rows0; if (rows > 256) rows = 256;
        gemm_bf16<128,128,64,64,false><<<dim3(VT/128, rows/128), 256, 0, stream>>>(
            H_bf + (size_t)rows0 * UU, fcWt, fc_b, logits, VT, UU, UU, UU);
        loss_kernel<<<rows, 256, 0, stream>>>(logits, targ, rows0, out);
    }
}

// Round 4
// 4156.069 us; speedup vs baseline: 5.3881x; 1.4024x over previous
//
#include <hip/hip_runtime.h>
#include <cstdint>
#include <cstddef>

#define BB 64      // batch
#define SS 50      // src len
#define TT 50      // tgt len
#define TD 49      // decoder steps
#define UU 1024    // hidden
#define EE 256     // embed
#define VT 16000   // tgt vocab
#define G3 3072    // 3*U
#define MPAD 3200  // 50*64 padded row count

using short8 = __attribute__((ext_vector_type(8))) short;
using uint4v = __attribute__((ext_vector_type(4))) unsigned int;
using f32x4  = __attribute__((ext_vector_type(4))) float;

__device__ __forceinline__ short f2bf(float f) {
    uint32_t u = __float_as_uint(f);
    uint32_t r = (u + 0x7fffu + ((u >> 16) & 1u)) >> 16;
    return (short)r;
}
__device__ __forceinline__ float bf2f(short s) {
    return __uint_as_float(((uint32_t)(uint16_t)s) << 16);
}
__device__ __forceinline__ float sigm(float x) { return 1.0f / (1.0f + __expf(-x)); }
__device__ __forceinline__ float ftanh(float x) {
    float xc = fminf(fmaxf(x, -8.0f), 8.0f);
    float e = __expf(2.0f * xc);
    return (e - 1.0f) / (e + 1.0f);
}

// ---- device-coherent (sc0+sc1) accesses for cross-block communication ----
__device__ __forceinline__ short8 vload16(const short* p) {
    union { uint4v u; short8 s; } c;
    c.u = *(const volatile uint4v*)p;
    return c.s;
}
__device__ __forceinline__ float4 vload_f4(const float* p) {
    union { uint4v u; float4 f; } c;
    c.u = *(const volatile uint4v*)p;
    return c.f;
}
__device__ __forceinline__ float vload_bf(const short* p) {
    return bf2f(*(const volatile short*)p);
}
__device__ __forceinline__ void vstore_bf(short* p, float v) {
    *(volatile short*)p = f2bf(v);
}
__device__ __forceinline__ void vstore_f(float* p, float v) {
    *(volatile float*)p = v;
}

// Lightweight grid barrier: monotonic counter, relaxed agent atomics, no cache
// flushes. All cross-block data uses volatile sc0/sc1 accesses, so no L2
// invalidate is needed — weights stay L2-resident across steps.
__device__ __forceinline__ void gbar(int* cnt, int target) {
    asm volatile("s_waitcnt vmcnt(0)" ::: "memory");  // drain my stores to LLC
    __syncthreads();
    if (threadIdx.x == 0) {
        __hip_atomic_fetch_add(cnt, 1, __ATOMIC_RELAXED, __HIP_MEMORY_SCOPE_AGENT);
        while (__hip_atomic_load(cnt, __ATOMIC_RELAXED, __HIP_MEMORY_SCOPE_AGENT) < target)
            __builtin_amdgcn_s_sleep(2);
    }
    __syncthreads();
}

typedef __attribute__((address_space(3))) void lds_vp;
typedef __attribute__((address_space(1))) void gl_vp;
__device__ __forceinline__ void gload16(void* lds, const void* g) {
    __builtin_amdgcn_global_load_lds((const gl_vp*)(uintptr_t)g,
                                     (lds_vp*)(uint32_t)(uintptr_t)lds,
                                     16, 0, 0);
}

__device__ __forceinline__ f32x4 mfma16(short8 a, short8 b, f32x4 c) {
    return __builtin_amdgcn_mfma_f32_16x16x32_bf16(a, b, c, 0, 0, 0);
}

// ---------------------------------------------------------------------------
// bf16 MFMA GEMM (parallel phases): C[m][n] = sum_k A[m][k]*Bt[n][k] (+bias)
// ---------------------------------------------------------------------------
template<int BM, int BN, int WM, int WN, bool OUT_BF16>
__global__ __launch_bounds__(256) void gemm_bf16(
    const short* __restrict__ A, const short* __restrict__ Bt,
    const float* __restrict__ bias, void* __restrict__ C, int N, int K,
    int lda, int ldb)
{
    constexpr int BK = 32;
    __shared__ __attribute__((aligned(16))) short As[BM * BK];
    __shared__ __attribute__((aligned(16))) short Bs[BN * BK];

    const int tid  = threadIdx.x;
    const int wave = tid >> 6;
    const int lane = tid & 63;
    const int l15  = lane & 15;
    const int quad = lane >> 4;
    const int wm = wave >> 1, wn = wave & 1;
    const int n0 = blockIdx.x * BN;
    const int m0 = blockIdx.y * BM;

    f32x4 acc[WM / 16][WN / 16];
    #pragma unroll
    for (int i = 0; i < WM / 16; ++i)
        #pragma unroll
        for (int j = 0; j < WN / 16; ++j)
            acc[i][j] = (f32x4)0.0f;

    for (int k0 = 0; k0 < K; k0 += BK) {
        #pragma unroll
        for (int it = 0; it < BM / 64; ++it) {
            int e = (it * 256 + tid) * 8;
            int row = e >> 5, col = e & 31;
            gload16(As + (it * 256 + wave * 64) * 8,
                    A + (size_t)(m0 + row) * lda + k0 + col);
        }
        #pragma unroll
        for (int it = 0; it < BN / 64; ++it) {
            int e = (it * 256 + tid) * 8;
            int row = e >> 5, col = e & 31;
            gload16(Bs + (it * 256 + wave * 64) * 8,
                    Bt + (size_t)(n0 + row) * ldb + k0 + col);
        }
        __syncthreads();
        short8 af[WM / 16], bfr[WN / 16];
        #pragma unroll
        for (int i = 0; i < WM / 16; ++i)
            af[i] = *(const short8*)(As + (wm * WM + i * 16 + l15) * BK + quad * 8);
        #pragma unroll
        for (int j = 0; j < WN / 16; ++j)
            bfr[j] = *(const short8*)(Bs + (wn * WN + j * 16 + l15) * BK + quad * 8);
        #pragma unroll
        for (int i = 0; i < WM / 16; ++i)
            #pragma unroll
            for (int j = 0; j < WN / 16; ++j)
                acc[i][j] = mfma16(af[i], bfr[j], acc[i][j]);
        __syncthreads();
    }

    #pragma unroll
    for (int i = 0; i < WM / 16; ++i) {
        #pragma unroll
        for (int j = 0; j < WN / 16; ++j) {
            int row = m0 + wm * WM + i * 16 + quad * 4;
            int col = n0 + wn * WN + j * 16 + l15;
            float bia = bias ? bias[col] : 0.0f;
            #pragma unroll
            for (int r = 0; r < 4; ++r) {
                size_t off = (size_t)(row + r) * N + col;
                float v = acc[i][j][r] + bia;
                if (OUT_BF16) ((short*)C)[off] = f2bf(v);
                else          ((float*)C)[off] = v;
            }
        }
    }
}

// ---------------------------------------------------------------------------
// Transpose fp32 [K][N] -> bf16 [N][K]
// ---------------------------------------------------------------------------
__global__ __launch_bounds__(256) void transpose_bf(
    const float* __restrict__ in, short* __restrict__ out, int ldin, int ldout)
{
    __shared__ float tile[64][65];
    int n0 = blockIdx.x * 64, k0 = blockIdx.y * 64;
    int c = threadIdx.x & 63, rr = threadIdx.x >> 6;
    #pragma unroll 4
    for (int i = 0; i < 16; ++i) {
        int row = rr * 16 + i;
        tile[row][c] = in[(size_t)(k0 + row) * ldin + n0 + c];
    }
    __syncthreads();
    #pragma unroll 4
    for (int i = 0; i < 16; ++i) {
        int row = rr * 16 + i;
        out[(size_t)(n0 + row) * ldout + k0 + c] = f2bf(tile[c][row]);
    }
}

// ---------------------------------------------------------------------------
// Pack bf16 Wt[N][K] (row-major, ld=K) into MFMA fragment-major layout:
// Wp[(((nt*(K/32) + it)*64 + lane)*8 + e] = Wt[nt*16 + (lane&15)][it*32 + (lane>>4)*8 + e]
// One coalesced 1KB wave-load per (nt, it) fragment at consumption time.
// Grid: ((K/32)/4, N/16), 256 threads.
// ---------------------------------------------------------------------------
__global__ __launch_bounds__(256) void pack_frag(
    const short* __restrict__ Wt, short* __restrict__ Wp, int K)
{
    int l  = threadIdx.x & 63;
    int it = blockIdx.x * 4 + (threadIdx.x >> 6);
    int nt = blockIdx.y;
    int KI = K >> 5;
    short8 v = *(const short8*)(Wt + (size_t)(nt * 16 + (l & 15)) * K + it * 32 + (l >> 4) * 8);
    *(short8*)(Wp + (((size_t)nt * KI + it) * 64 + l) * 8) = v;
}

// ---------------------------------------------------------------------------
// Prep: gather embeddings to bf16, convert h0, zero pads, zero out + barriers.
// ---------------------------------------------------------------------------
__global__ __launch_bounds__(256) void prep_gather(
    const int* __restrict__ inp, const int* __restrict__ targ,
    const float* __restrict__ enc_emb, const float* __restrict__ dec_emb,
    const float* __restrict__ enc_h0,
    short* __restrict__ Ae, short* __restrict__ Ad,
    short* __restrict__ H_bf, short* __restrict__ h0_bf,
    float* __restrict__ out, int* __restrict__ bar)
{
    int blk = blockIdx.x, tid = threadIdx.x;
    if (blk < MPAD) {
        int s = blk >> 6, b = blk & 63;
        int row = inp[b * SS + s];
        Ae[(size_t)blk * EE + tid] = f2bf(enc_emb[(size_t)row * EE + tid]);
    } else if (blk < 2 * MPAD) {
        int m = blk - MPAD;
        if (m < TD * BB) {
            int t = m >> 6, b = m & 63;
            int row = targ[b * TT + t];
            Ad[(size_t)m * EE + tid] = f2bf(dec_emb[(size_t)row * EE + tid]);
        } else {
            Ad[(size_t)m * EE + tid] = 0;
        }
    } else {
        int r = blk - 2 * MPAD;  // 0..63
        for (int u = tid; u < UU; u += 256) {
            H_bf[(size_t)(TD * BB + r) * UU + u] = 0;   // fc pad rows
            h0_bf[(size_t)r * UU + u] = f2bf(enc_h0[(size_t)r * UU + u]);
        }
        if (r == 0 && tid == 0) { out[0] = 0.0f; bar[0] = 0; bar[1] = 0; }
    }
}

// ---------------------------------------------------------------------------
// Encoder persistent scan. 64 blocks x 1024 threads (16 waves).
// Block j owns u-cols [j*16, j*16+16). wave = (bg, kq): bg = batch-row group
// (16 rows), kq = k-quarter (256 of K=1024). LDS f32x4 reduction over kq.
// Communicated data (h) via volatile sc0sc1; weights stay L2-cached.
// ---------------------------------------------------------------------------
__global__ __launch_bounds__(1024) void enc_scan(
    const short* __restrict__ h0, const short* __restrict__ Whp,
    const short* __restrict__ gi, const float* __restrict__ bias2,
    short* __restrict__ eout, int* __restrict__ bar)
{
    const int j    = blockIdx.x;
    const int tid  = threadIdx.x;
    const int wave = tid >> 6;
    const int lane = tid & 63;
    const int l15  = lane & 15;
    const int quad = lane >> 4;
    const int bg   = wave & 3;
    const int kq   = wave >> 2;
    const int u    = j * 16 + l15;

    __shared__ f32x4 red[4][3][4][64];   // [kq][gate][bg][lane]

    // packed B: nt = g*64 + j, it = kq*8 + i ; stride per i = 512 shorts
    const short* Bp0 = Whp + ((((size_t)(0 * 64 + j)) * 32 + kq * 8) * 64 + lane) * 8;
    const short* Bp1 = Whp + ((((size_t)(1 * 64 + j)) * 32 + kq * 8) * 64 + lane) * 8;
    const short* Bp2 = Whp + ((((size_t)(2 * 64 + j)) * 32 + kq * 8) * 64 + lane) * 8;
    const float bz = bias2[u], br = bias2[UU + u], bh = bias2[2 * UU + u];

    for (int t = 0; t < SS; ++t) {
        const short* A = t ? eout + (size_t)(t - 1) * BB * UU : h0;
        const short* Arow = A + (size_t)(bg * 16 + l15) * UU + kq * 256 + quad * 8;
        f32x4 a0 = (f32x4)0.0f, a1 = (f32x4)0.0f, a2 = (f32x4)0.0f;
        #pragma unroll
        for (int i = 0; i < 8; ++i) {
            short8 af = vload16(Arow + i * 32);
            a0 = mfma16(af, *(const short8*)(Bp0 + i * 512), a0);
            a1 = mfma16(af, *(const short8*)(Bp1 + i * 512), a1);
            a2 = mfma16(af, *(const short8*)(Bp2 + i * 512), a2);
        }
        red[kq][0][bg][lane] = a0;
        red[kq][1][bg][lane] = a1;
        red[kq][2][bg][lane] = a2;
        __syncthreads();
        if (kq == 0) {
            f32x4 s0 = red[0][0][bg][lane] + red[1][0][bg][lane] + red[2][0][bg][lane] + red[3][0][bg][lane];
            f32x4 s1 = red[0][1][bg][lane] + red[1][1][bg][lane] + red[2][1][bg][lane] + red[3][1][bg][lane];
            f32x4 s2 = red[0][2][bg][lane] + red[1][2][bg][lane] + red[2][2][bg][lane] + red[3][2][bg][lane];
            const short* git = gi + (size_t)t * BB * G3;
            #pragma unroll
            for (int r = 0; r < 4; ++r) {
                int b = bg * 16 + quad * 4 + r;
                const short* gb = git + (size_t)b * G3;
                float iz = bf2f(gb[u]), ir = bf2f(gb[UU + u]), ih = bf2f(gb[2 * UU + u]);
                float h = vload_bf(A + (size_t)b * UU + u);
                float z  = sigm(iz + s0[r] + bz);
                float rr = sigm(ir + s1[r] + br);
                float hc = ftanh(ih + rr * (s2[r] + bh));
                vstore_bf(eout + (size_t)t * BB * UU + (size_t)b * UU + u,
                          z * h + (1.0f - z) * hc);
            }
        }
        if (t != SS - 1) gbar(bar, (t + 1) * 64);
    }
}

// ---------------------------------------------------------------------------
// Decoder persistent scan. 64 blocks x 1024 threads. 3 phases / 3 barriers:
//  P1: q = dh @ W1 + b1 (block j: u-slice, k-split over waves)
//  P2: attention (block = batch b)
//  P3: gi = ctx @ dWx_c + xemb_gi; GRU(h=0) -> H[t]
// ---------------------------------------------------------------------------
__global__ __launch_bounds__(1024) void dec_scan(
    const short* __restrict__ eout, const short* __restrict__ W1p,
    const float* __restrict__ b1, const short* __restrict__ keysb,
    const float* __restrict__ Vw, const float* __restrict__ bV,
    const short* __restrict__ dWxp, const short* __restrict__ xg,
    const float* __restrict__ db1, float* __restrict__ qb,
    short* __restrict__ ctxb, short* __restrict__ Hbf, int* __restrict__ bar)
{
    const int j    = blockIdx.x;
    const int tid  = threadIdx.x;
    const int wave = tid >> 6;
    const int lane = tid & 63;
    const int l15  = lane & 15;
    const int quad = lane >> 4;
    const int bg   = wave & 3;
    const int kq   = wave >> 2;
    const int u    = j * 16 + l15;

    __shared__ f32x4 red[4][3][4][64];
    __shared__ float sc[64];
    __shared__ float attnw[64];

    const short* BpQ  = W1p  + (((size_t)j * 32 + kq * 8) * 64 + lane) * 8;
    const short* BpC0 = dWxp + ((((size_t)(0 * 64 + j)) * 32 + kq * 8) * 64 + lane) * 8;
    const short* BpC1 = dWxp + ((((size_t)(1 * 64 + j)) * 32 + kq * 8) * 64 + lane) * 8;
    const short* BpC2 = dWxp + ((((size_t)(2 * 64 + j)) * 32 + kq * 8) * 64 + lane) * 8;
    const float b1v = b1[u];
    const float dz = db1[u], dr = db1[UU + u], dhh = db1[2 * UU + u];
    const float bV0 = bV[0];

    float Vl[16];
    #pragma unroll
    for (int e = 0; e < 16; e += 4)
        *(float4*)&Vl[e] = *(const float4*)(Vw + lane * 16 + e);

    int ph = 0;
    for (int t = 0; t < TD; ++t) {
        const short* dh = t ? Hbf + (size_t)(t - 1) * BB * UU
                            : eout + (size_t)(SS - 1) * BB * UU;
        // ---- P1: q slice ----
        {
            const short* Arow = dh + (size_t)(bg * 16 + l15) * UU + kq * 256 + quad * 8;
            f32x4 aq = (f32x4)0.0f;
            #pragma unroll
            for (int i = 0; i < 8; ++i)
                aq = mfma16(vload16(Arow + i * 32), *(const short8*)(BpQ + i * 512), aq);
            red[kq][0][bg][lane] = aq;
        }
        __syncthreads();
        if (kq == 0) {
            f32x4 s = red[0][0][bg][lane] + red[1][0][bg][lane] + red[2][0][bg][lane] + red[3][0][bg][lane];
            #pragma unroll
            for (int r = 0; r < 4; ++r)
                vstore_f(qb + (size_t)(bg * 16 + quad * 4 + r) * UU + u, s[r] + b1v);
        }
        gbar(bar, ++ph * 64);
        // ---- P2: attention, block = batch b = j ----
        {
            const int b = j;
            float ql[16];
            #pragma unroll
            for (int e = 0; e < 16; e += 4)
                *(float4*)&ql[e] = vload_f4(qb + (size_t)b * UU + lane * 16 + e);
            for (int s = wave; s < SS; s += 16) {
                const short* kp = keysb + ((size_t)s * BB + b) * UU + lane * 16;
                short8 k0 = *(const short8*)kp;
                short8 k1 = *(const short8*)(kp + 8);
                float p = 0.0f;
                #pragma unroll
                for (int e = 0; e < 8; ++e) p += Vl[e] * ftanh(ql[e] + bf2f(k0[e]));
                #pragma unroll
                for (int e = 0; e < 8; ++e) p += Vl[8 + e] * ftanh(ql[8 + e] + bf2f(k1[e]));
                #pragma unroll
                for (int off = 32; off; off >>= 1) p += __shfl_down(p, off);
                if (lane == 0) sc[s] = p + bV0;
            }
            __syncthreads();
            if (wave == 0) {
                float v = (lane < SS) ? sc[lane] : -1e30f;
                float m = v;
                #pragma unroll
                for (int off = 32; off; off >>= 1) m = fmaxf(m, __shfl_down(m, off));
                m = __shfl(m, 0);
                float e = (lane < SS) ? __expf(v - m) : 0.0f;
                float ss = e;
                #pragma unroll
                for (int off = 32; off; off >>= 1) ss += __shfl_down(ss, off);
                ss = __shfl(ss, 0);
                if (lane < SS) attnw[lane] = e / ss;
            }
            __syncthreads();
            float acc = 0.0f;
            #pragma unroll 2
            for (int s = 0; s < SS; ++s)
                acc += attnw[s] * bf2f(eout[((size_t)s * BB + b) * UU + tid]);
            vstore_bf(ctxb + (size_t)b * UU + tid, acc);
        }
        gbar(bar, ++ph * 64);
        // ---- P3: gi slice + GRU(h=0) pointwise ----
        {
            const short* Arow = ctxb + (size_t)(bg * 16 + l15) * UU + kq * 256 + quad * 8;
            f32x4 a0 = (f32x4)0.0f, a1 = (f32x4)0.0f, a2 = (f32x4)0.0f;
            #pragma unroll
            for (int i = 0; i < 8; ++i) {
                short8 af = vload16(Arow + i * 32);
                a0 = mfma16(af, *(const short8*)(BpC0 + i * 512), a0);
                a1 = mfma16(af, *(const short8*)(BpC1 + i * 512), a1);
                a2 = mfma16(af, *(const short8*)(BpC2 + i * 512), a2);
            }
            red[kq][0][bg][lane] = a0;
            red[kq][1][bg][lane] = a1;
            red[kq][2][bg][lane] = a2;
            __syncthreads();
            if (kq == 0) {
                f32x4 s0 = red[0][0][bg][lane] + red[1][0][bg][lane] + red[2][0][bg][lane] + red[3][0][bg][lane];
                f32x4 s1 = red[0][1][bg][lane] + red[1][1][bg][lane] + red[2][1][bg][lane] + red[3][1][bg][lane];
                f32x4 s2 = red[0][2][bg][lane] + red[1][2][bg][lane] + red[2][2][bg][lane] + red[3][2][bg][lane];
                const short* xgt = xg + (size_t)t * BB * G3;
                #pragma unroll
                for (int r = 0; r < 4; ++r) {
                    int b = bg * 16 + quad * 4 + r;
                    const short* xb = xgt + (size_t)b * G3;
                    float g0 = s0[r] + bf2f(xb[u]);
                    float g1 = s1[r] + bf2f(xb[UU + u]);
                    float g2 = s2[r] + bf2f(xb[2 * UU + u]);
                    float z  = sigm(g0 + dz);
                    float rr = sigm(g1 + dr);
                    float hc = ftanh(g2 + rr * dhh);
                    vstore_bf(Hbf + (size_t)t * BB * UU + (size_t)b * UU + u,
                              (1.0f - z) * hc);
                }
            }
        }
        ++ph;
        if (t != TD - 1) gbar(bar, ph * 64);
    }
}

// ---------------------------------------------------------------------------
// Loss over one logits chunk.
// ---------------------------------------------------------------------------
__global__ __launch_bounds__(256) void loss_kernel(
    const float* __restrict__ logits, const int* __restrict__ targ,
    int rows0, float* __restrict__ out)
{
    int gr = rows0 + blockIdx.x;
    int t = gr >> 6;
    if (t >= TD) return;
    int b = gr & 63;
    const float* lp = logits + (size_t)blockIdx.x * VT;
    int tid = threadIdx.x;
    __shared__ float redm[4], reds[4];

    float m = -INFINITY;
    for (int v = tid; v < VT; v += 256) m = fmaxf(m, lp[v]);
    #pragma unroll
    for (int off = 32; off; off >>= 1) m = fmaxf(m, __shfl_down(m, off));
    if ((tid & 63) == 0) redm[tid >> 6] = m;
    __syncthreads();
    float mm = fmaxf(fmaxf(redm[0], redm[1]), fmaxf(redm[2], redm[3]));

    float ssum = 0.0f;
    for (int v = tid; v < VT; v += 256) ssum += expf(lp[v] - mm);
    #pragma unroll
    for (int off = 32; off; off >>= 1) ssum += __shfl_down(ssum, off);
    if ((tid & 63) == 0) reds[tid >> 6] = ssum;
    __syncthreads();
    if (tid == 0) {
        float tot = reds[0] + reds[1] + reds[2] + reds[3];
        int y = targ[b * TT + t + 1];
        float nll = mm + logf(tot) - lp[y];
        if (y != 0) atomicAdd(out, nll * (1.0f / (float)BB));
    }
}

// ---------------------------------------------------------------------------
extern "C" void kernel_launch(void* const* d_in, const int* in_sizes, int n_in,
                              void* d_out, int out_size, void* d_ws, size_t ws_size,
                              hipStream_t stream)
{
    (void)in_sizes; (void)n_in; (void)out_size; (void)ws_size;
    const int*   inp      = (const int*)  d_in[0];
    const int*   targ     = (const int*)  d_in[1];
    const float* enc_h0   = (const float*)d_in[2];
    const float* enc_emb  = (const float*)d_in[3];
    const float* enc_Wx   = (const float*)d_in[4];
    const float* enc_Wh   = (const float*)d_in[5];
    const float* enc_b    = (const float*)d_in[6];
    const float* W1       = (const float*)d_in[7];
    const float* b1       = (const float*)d_in[8];
    const float* W2       = (const float*)d_in[9];
    const float* b2       = (const float*)d_in[10];
    const float* Vw       = (const float*)d_in[11];
    const float* bV       = (const float*)d_in[12];
    const float* dec_emb  = (const float*)d_in[13];
    const float* dec_Wx   = (const float*)d_in[14];
    /* dec_Wh (d_in[15]) mathematically unused: decoder GRU gets h==0 */
    const float* dec_b    = (const float*)d_in[16];
    const float* fc_W     = (const float*)d_in[17];
    const float* fc_b     = (const float*)d_in[18];
    float* out = (float*)d_out;

    char* p = (char*)d_ws;
    auto alloc = [&](size_t bytes) {
        char* r = (char*)(((uintptr_t)p + 255) & ~(uintptr_t)255);
        p = r + bytes;
        return r;
    };
    short* encWxt  = (short*)alloc((size_t)G3 * EE * 2);
    short* encWht  = (short*)alloc((size_t)G3 * UU * 2);
    short* W1t     = (short*)alloc((size_t)UU * UU * 2);
    short* W2t     = (short*)alloc((size_t)UU * UU * 2);
    short* dWxt_c  = (short*)alloc((size_t)G3 * UU * 2);
    short* dWxt_e  = (short*)alloc((size_t)G3 * EE * 2);
    short* fcWt    = (short*)alloc((size_t)VT * UU * 2);
    short* encWhp  = (short*)alloc((size_t)G3 * UU * 2);   // fragment-packed
    short* W1p     = (short*)alloc((size_t)UU * UU * 2);
    short* dWxp    = (short*)alloc((size_t)G3 * UU * 2);
    short* Ae      = (short*)alloc((size_t)MPAD * EE * 2);
    short* Ad      = (short*)alloc((size_t)MPAD * EE * 2);
    short* enc_gi  = (short*)alloc((size_t)MPAD * G3 * 2);
    short* xemb_gi = (short*)alloc((size_t)MPAD * G3 * 2);
    short* enc_out = (short*)alloc((size_t)MPAD * UU * 2);
    short* keysb   = (short*)alloc((size_t)MPAD * UU * 2);
    short* H_bf    = (short*)alloc((size_t)MPAD * UU * 2);
    short* h0_bf   = (short*)alloc((size_t)BB * UU * 2);
    float* qb      = (float*)alloc((size_t)BB * UU * 4);
    short* ctx_bf  = (short*)alloc((size_t)BB * UU * 2);
    float* logits  = (float*)alloc((size_t)256 * VT * 4);
    int*   bar     = (int*)alloc(256);

    // --- one-time prep (parallel) ---
    transpose_bf<<<dim3(G3/64, EE/64), 256, 0, stream>>>(enc_Wx, encWxt, G3, EE);
    transpose_bf<<<dim3(G3/64, UU/64), 256, 0, stream>>>(enc_Wh, encWht, G3, UU);
    transpose_bf<<<dim3(UU/64, UU/64), 256, 0, stream>>>(W1, W1t, UU, UU);
    transpose_bf<<<dim3(UU/64, UU/64), 256, 0, stream>>>(W2, W2t, UU, UU);
    transpose_bf<<<dim3(G3/64, UU/64), 256, 0, stream>>>(dec_Wx, dWxt_c, G3, UU);
    transpose_bf<<<dim3(G3/64, EE/64), 256, 0, stream>>>(dec_Wx + (size_t)UU * G3, dWxt_e, G3, EE);
    transpose_bf<<<dim3(VT/64, UU/64), 256, 0, stream>>>(fc_W, fcWt, VT, UU);
    pack_frag<<<dim3(8, G3/16), 256, 0, stream>>>(encWht, encWhp, UU);
    pack_frag<<<dim3(8, UU/16), 256, 0, stream>>>(W1t, W1p, UU);
    pack_frag<<<dim3(8, G3/16), 256, 0, stream>>>(dWxt_c, dWxp, UU);
    prep_gather<<<2 * MPAD + 64, 256, 0, stream>>>(inp, targ, enc_emb, dec_emb, enc_h0,
                                                   Ae, Ad, H_bf, h0_bf, out, bar);

    gemm_bf16<128,128,64,64,true><<<dim3(G3/128, MPAD/128), 256, 0, stream>>>(
        Ae, encWxt, enc_b, enc_gi, G3, EE, EE, EE);
    gemm_bf16<128,128,64,64,true><<<dim3(G3/128, MPAD/128), 256, 0, stream>>>(
        Ad, dWxt_e, dec_b, xemb_gi, G3, EE, EE, EE);

    // --- encoder persistent scan (cooperative launch for co-residency) ---
    {
        const short* a0 = h0_bf; const short* a1 = encWhp; const short* a2 = enc_gi;
        const float* a3 = enc_b + G3; short* a4 = enc_out; int* a5 = bar;
        void* args[] = {&a0, &a1, &a2, &a3, &a4, &a5};
        hipLaunchCooperativeKernel((void*)enc_scan, dim3(64), dim3(1024), args, 0, stream);
    }

    // keys = enc_out @ W2 + b2  (bf16)
    gemm_bf16<128,128,64,64,true><<<dim3(UU/128, MPAD/128), 256, 0, stream>>>(
        enc_out, W2t, b2, keysb, UU, UU, UU, UU);

    // --- decoder persistent scan (cooperative) ---
    {
        const short* a0 = enc_out; const short* a1 = W1p; const float* a2 = b1;
        const short* a3 = keysb; const float* a4 = Vw; const float* a5 = bV;
        const short* a6 = dWxp; const short* a7 = xemb_gi; const float* a8 = dec_b + G3;
        float* a9 = qb; short* a10 = ctx_bf; short* a11 = H_bf; int* a12 = bar + 1;
        void* args[] = {&a0, &a1, &a2, &a3, &a4, &a5, &a6, &a7, &a8, &a9, &a10, &a11, &a12};
        hipLaunchCooperativeKernel((void*)dec_scan, dim3(64), dim3(1024), args, 0, stream);
    }

    // --- fc + loss, chunks of 256 rows ---
    for (int rows0 = 0; rows0 < MPAD; rows0 += 256) {
        int rows = MPAD - rows0; if (rows > 256) rows = 256;
        gemm_bf16<128,128,64,64,false><<<dim3(VT/128, rows/128), 256, 0, stream>>>(
            H_bf + (size_t)rows0 * UU, fcWt, fc_b, logits, VT, UU, UU, UU);
        loss_kernel<<<rows, 256, 0, stream>>>(logits, targ, rows0, out);
    }
}

// Round 5
// 3821.051 us; speedup vs baseline: 5.8606x; 1.0877x over previous
//
#include <hip/hip_runtime.h>
#include <cstdint>
#include <cstddef>

#define BB 64      // batch
#define SS 50      // src len
#define TT 50      // tgt len
#define TD 49      // decoder steps
#define UU 1024    // hidden
#define EE 256     // embed
#define VT 16000   // tgt vocab
#define G3 3072    // 3*U
#define MPAD 3200  // 50*64 padded row count

using short8 = __attribute__((ext_vector_type(8))) short;
using uint4v = __attribute__((ext_vector_type(4))) unsigned int;
using f32x4  = __attribute__((ext_vector_type(4))) float;

__device__ __forceinline__ short f2bf(float f) {
    uint32_t u = __float_as_uint(f);
    uint32_t r = (u + 0x7fffu + ((u >> 16) & 1u)) >> 16;
    return (short)r;
}
__device__ __forceinline__ float bf2f(short s) {
    return __uint_as_float(((uint32_t)(uint16_t)s) << 16);
}
__device__ __forceinline__ float sigm(float x) { return 1.0f / (1.0f + __expf(-x)); }
__device__ __forceinline__ float ftanh(float x) {
    float xc = fminf(fmaxf(x, -8.0f), 8.0f);
    float e = __expf(2.0f * xc);
    return (e - 1.0f) / (e + 1.0f);
}

// ---- cache-bypassing accesses for data written by other blocks in-kernel ----
__device__ __forceinline__ short8 vload16(const short* p) {
    union { uint4v u; short8 s; } c;
    c.u = *(const volatile uint4v*)p;
    return c.s;
}
__device__ __forceinline__ float vload_f(const float* p) { return *(const volatile float*)p; }
__device__ __forceinline__ float vload_bf(const short* p) { return bf2f(*(const volatile short*)p); }
__device__ __forceinline__ void vstore_bf(short* p, float v) { *(volatile short*)p = f2bf(v); }
__device__ __forceinline__ void vstore_f(float* p, float v) { *(volatile float*)p = v; }

// Contention-free grid barrier: per-block arrival flags (plain relaxed stores,
// no RMW), leader block ballot-polls all 64 flags, releases via `go` word.
__device__ __forceinline__ void gbar(int* flags, int* go, int t) {
    asm volatile("s_waitcnt vmcnt(0)" ::: "memory");   // my data stores drained
    __syncthreads();
    if (blockIdx.x == 0) {
        if (threadIdx.x < 64) {
            if (threadIdx.x == 0)
                __hip_atomic_store(&flags[0], t, __ATOMIC_RELAXED, __HIP_MEMORY_SCOPE_AGENT);
            int v;
            do {
                v = __hip_atomic_load(&flags[threadIdx.x], __ATOMIC_RELAXED, __HIP_MEMORY_SCOPE_AGENT);
            } while (__ballot(v >= t) != ~0ull);
            if (threadIdx.x == 0)
                __hip_atomic_store(go, t, __ATOMIC_RELAXED, __HIP_MEMORY_SCOPE_AGENT);
        }
    } else {
        if (threadIdx.x == 0) {
            __hip_atomic_store(&flags[blockIdx.x], t, __ATOMIC_RELAXED, __HIP_MEMORY_SCOPE_AGENT);
            while (__hip_atomic_load(go, __ATOMIC_RELAXED, __HIP_MEMORY_SCOPE_AGENT) < t)
                __builtin_amdgcn_s_sleep(1);
        }
    }
    __syncthreads();
}

typedef __attribute__((address_space(3))) void lds_vp;
typedef __attribute__((address_space(1))) void gl_vp;
__device__ __forceinline__ void gload16(void* lds, const void* g) {
    __builtin_amdgcn_global_load_lds((const gl_vp*)(uintptr_t)g,
                                     (lds_vp*)(uint32_t)(uintptr_t)lds,
                                     16, 0, 0);
}
__device__ __forceinline__ f32x4 mfma16(short8 a, short8 b, f32x4 c) {
    return __builtin_amdgcn_mfma_f32_16x16x32_bf16(a, b, c, 0, 0, 0);
}

// ---------------------------------------------------------------------------
// bf16 MFMA GEMM (parallel phases): C[m][n] = sum_k A[m][k]*Bt[n][k] (+bias)
// ---------------------------------------------------------------------------
template<int BM, int BN, int WM, int WN, bool OUT_BF16>
__global__ __launch_bounds__(256) void gemm_bf16(
    const short* __restrict__ A, const short* __restrict__ Bt,
    const float* __restrict__ bias, void* __restrict__ C, int N, int K,
    int lda, int ldb)
{
    constexpr int BK = 32;
    __shared__ __attribute__((aligned(16))) short As[BM * BK];
    __shared__ __attribute__((aligned(16))) short Bs[BN * BK];

    const int tid  = threadIdx.x;
    const int wave = tid >> 6;
    const int lane = tid & 63;
    const int l15  = lane & 15;
    const int quad = lane >> 4;
    const int wm = wave >> 1, wn = wave & 1;
    const int n0 = blockIdx.x * BN;
    const int m0 = blockIdx.y * BM;

    f32x4 acc[WM / 16][WN / 16];
    #pragma unroll
    for (int i = 0; i < WM / 16; ++i)
        #pragma unroll
        for (int j = 0; j < WN / 16; ++j)
            acc[i][j] = (f32x4)0.0f;

    for (int k0 = 0; k0 < K; k0 += BK) {
        #pragma unroll
        for (int it = 0; it < BM / 64; ++it) {
            int e = (it * 256 + tid) * 8;
            int row = e >> 5, col = e & 31;
            gload16(As + (it * 256 + wave * 64) * 8,
                    A + (size_t)(m0 + row) * lda + k0 + col);
        }
        #pragma unroll
        for (int it = 0; it < BN / 64; ++it) {
            int e = (it * 256 + tid) * 8;
            int row = e >> 5, col = e & 31;
            gload16(Bs + (it * 256 + wave * 64) * 8,
                    Bt + (size_t)(n0 + row) * ldb + k0 + col);
        }
        __syncthreads();
        short8 af[WM / 16], bfr[WN / 16];
        #pragma unroll
        for (int i = 0; i < WM / 16; ++i)
            af[i] = *(const short8*)(As + (wm * WM + i * 16 + l15) * BK + quad * 8);
        #pragma unroll
        for (int j = 0; j < WN / 16; ++j)
            bfr[j] = *(const short8*)(Bs + (wn * WN + j * 16 + l15) * BK + quad * 8);
        #pragma unroll
        for (int i = 0; i < WM / 16; ++i)
            #pragma unroll
            for (int j = 0; j < WN / 16; ++j)
                acc[i][j] = mfma16(af[i], bfr[j], acc[i][j]);
        __syncthreads();
    }

    #pragma unroll
    for (int i = 0; i < WM / 16; ++i) {
        #pragma unroll
        for (int j = 0; j < WN / 16; ++j) {
            int row = m0 + wm * WM + i * 16 + quad * 4;
            int col = n0 + wn * WN + j * 16 + l15;
            float bia = bias ? bias[col] : 0.0f;
            #pragma unroll
            for (int r = 0; r < 4; ++r) {
                size_t off = (size_t)(row + r) * N + col;
                float v = acc[i][j][r] + bia;
                if (OUT_BF16) ((short*)C)[off] = f2bf(v);
                else          ((float*)C)[off] = v;
            }
        }
    }
}

// ---------------------------------------------------------------------------
// Transpose fp32 [K][N] -> bf16 [N][K]
// ---------------------------------------------------------------------------
__global__ __launch_bounds__(256) void transpose_bf(
    const float* __restrict__ in, short* __restrict__ out, int ldin, int ldout)
{
    __shared__ float tile[64][65];
    int n0 = blockIdx.x * 64, k0 = blockIdx.y * 64;
    int c = threadIdx.x & 63, rr = threadIdx.x >> 6;
    #pragma unroll 4
    for (int i = 0; i < 16; ++i) {
        int row = rr * 16 + i;
        tile[row][c] = in[(size_t)(k0 + row) * ldin + n0 + c];
    }
    __syncthreads();
    #pragma unroll 4
    for (int i = 0; i < 16; ++i) {
        int row = rr * 16 + i;
        out[(size_t)(n0 + row) * ldout + k0 + c] = f2bf(tile[c][row]);
    }
}

// ---------------------------------------------------------------------------
// Pack bf16 Wt[N][K] into MFMA fragment-major: one 1KB wave-load per fragment.
// ---------------------------------------------------------------------------
__global__ __launch_bounds__(256) void pack_frag(
    const short* __restrict__ Wt, short* __restrict__ Wp, int K)
{
    int l  = threadIdx.x & 63;
    int it = blockIdx.x * 4 + (threadIdx.x >> 6);
    int nt = blockIdx.y;
    int KI = K >> 5;
    short8 v = *(const short8*)(Wt + (size_t)(nt * 16 + (l & 15)) * K + it * 32 + (l >> 4) * 8);
    *(short8*)(Wp + (((size_t)nt * KI + it) * 64 + l) * 8) = v;
}

// ---------------------------------------------------------------------------
// Prep: gather embeddings, convert h0, zero pads/out/barriers.
// ---------------------------------------------------------------------------
__global__ __launch_bounds__(256) void prep_gather(
    const int* __restrict__ inp, const int* __restrict__ targ,
    const float* __restrict__ enc_emb, const float* __restrict__ dec_emb,
    const float* __restrict__ enc_h0,
    short* __restrict__ Ae, short* __restrict__ Ad,
    short* __restrict__ H_bf, short* __restrict__ h0_bf,
    float* __restrict__ out, int* __restrict__ bar)
{
    int blk = blockIdx.x, tid = threadIdx.x;
    if (blk < MPAD) {
        int s = blk >> 6, b = blk & 63;
        int row = inp[b * SS + s];
        Ae[(size_t)blk * EE + tid] = f2bf(enc_emb[(size_t)row * EE + tid]);
    } else if (blk < 2 * MPAD) {
        int m = blk - MPAD;
        if (m < TD * BB) {
            int t = m >> 6, b = m & 63;
            int row = targ[b * TT + t];
            Ad[(size_t)m * EE + tid] = f2bf(dec_emb[(size_t)row * EE + tid]);
        } else {
            Ad[(size_t)m * EE + tid] = 0;
        }
    } else {
        int r = blk - 2 * MPAD;  // 0..63
        for (int u = tid; u < UU; u += 256) {
            H_bf[(size_t)(TD * BB + r) * UU + u] = 0;   // fc pad rows
            h0_bf[(size_t)r * UU + u] = f2bf(enc_h0[(size_t)r * UU + u]);
        }
        if (r == 0) {
            bar[tid] = 0;                                // 256 barrier words
            if (tid == 0) out[0] = 0.0f;
        }
    }
}

// ---------------------------------------------------------------------------
// Encoder persistent scan. 64 blocks x 1024 threads. Block j owns u-cols
// [j*16,(j+1)*16). wave=(bg,kq). Weights read from L2 (fragment-packed).
// ---------------------------------------------------------------------------
__global__ __launch_bounds__(1024) void enc_scan(
    const short* __restrict__ h0, const short* __restrict__ Whp,
    const short* __restrict__ gi, const float* __restrict__ bias2,
    short* __restrict__ eout, int* __restrict__ bar)
{
    const int j    = blockIdx.x;
    const int tid  = threadIdx.x;
    const int lane = tid & 63;
    const int l15  = lane & 15;
    const int quad = lane >> 4;
    const int wave = tid >> 6;
    const int bg   = wave & 3;
    const int kq   = wave >> 2;
    const int u    = j * 16 + l15;

    __shared__ f32x4 red[4][3][4][64];   // [kq][gate][bg][lane]
    int* flags = bar;     int* go = bar + 64;

    const short* Bp0 = Whp + ((((size_t)(0 * 64 + j)) * 32 + kq * 8) * 64 + lane) * 8;
    const short* Bp1 = Whp + ((((size_t)(1 * 64 + j)) * 32 + kq * 8) * 64 + lane) * 8;
    const short* Bp2 = Whp + ((((size_t)(2 * 64 + j)) * 32 + kq * 8) * 64 + lane) * 8;
    const float bz = bias2[u], br = bias2[UU + u], bh = bias2[2 * UU + u];

    for (int t = 0; t < SS; ++t) {
        const short* A = t ? eout + (size_t)(t - 1) * BB * UU : h0;
        const short* Arow = A + (size_t)(bg * 16 + l15) * UU + kq * 256 + quad * 8;
        f32x4 a0 = (f32x4)0.0f, a1 = (f32x4)0.0f, a2 = (f32x4)0.0f;
        #pragma unroll
        for (int i = 0; i < 8; ++i) {
            short8 af = vload16(Arow + i * 32);
            a0 = mfma16(af, *(const short8*)(Bp0 + i * 512), a0);
            a1 = mfma16(af, *(const short8*)(Bp1 + i * 512), a1);
            a2 = mfma16(af, *(const short8*)(Bp2 + i * 512), a2);
        }
        red[kq][0][bg][lane] = a0;
        red[kq][1][bg][lane] = a1;
        red[kq][2][bg][lane] = a2;
        __syncthreads();
        if (kq == 0) {
            f32x4 s0 = red[0][0][bg][lane] + red[1][0][bg][lane] + red[2][0][bg][lane] + red[3][0][bg][lane];
            f32x4 s1 = red[0][1][bg][lane] + red[1][1][bg][lane] + red[2][1][bg][lane] + red[3][1][bg][lane];
            f32x4 s2 = red[0][2][bg][lane] + red[1][2][bg][lane] + red[2][2][bg][lane] + red[3][2][bg][lane];
            const short* git = gi + (size_t)t * BB * G3;
            #pragma unroll
            for (int r = 0; r < 4; ++r) {
                int b = bg * 16 + quad * 4 + r;
                const short* gb = git + (size_t)b * G3;
                float iz = bf2f(gb[u]), ir = bf2f(gb[UU + u]), ih = bf2f(gb[2 * UU + u]);
                float h = vload_bf(A + (size_t)b * UU + u);
                float z  = sigm(iz + s0[r] + bz);
                float rr = sigm(ir + s1[r] + br);
                float hc = ftanh(ih + rr * (s2[r] + bh));
                vstore_bf(eout + (size_t)t * BB * UU + (size_t)b * UU + u,
                          z * h + (1.0f - z) * hc);
            }
        }
        if (t != SS - 1) gbar(flags, go, t + 1);
    }
}

// ---------------------------------------------------------------------------
// Decoder persistent scan. 64 blocks x 1024 threads. Per step:
//  P1: q = dh @ W1 + b1   (block j: u-slice; k-split over waves)  -> q_bf
//  P2: block b: scores over full q + keys, softmax -> attn_g[b][50]
//  P3: block j: gi = sum_s attn*P (+xemb_gi), GRU(h=0) -> Hbf[t]
// P = eout @ dWx_ctx precomputed (ctx GEMM algebraically eliminated).
// ---------------------------------------------------------------------------
__global__ __launch_bounds__(1024) void dec_scan(
    const short* __restrict__ eout, const short* __restrict__ W1p,
    const float* __restrict__ b1, const short* __restrict__ keysb,
    const float* __restrict__ Vw, const float* __restrict__ bV,
    const short* __restrict__ P, const short* __restrict__ xg,
    const float* __restrict__ db1, short* __restrict__ q_bf,
    float* __restrict__ attn_g, short* __restrict__ Hbf, int* __restrict__ bar)
{
    const int j    = blockIdx.x;
    const int tid  = threadIdx.x;
    const int lane = tid & 63;
    const int l15  = lane & 15;
    const int quad = lane >> 4;
    const int wave = tid >> 6;
    const int bg   = wave & 3;
    const int kq   = wave >> 2;
    const int u    = j * 16 + l15;

    __shared__ f32x4 redq[4][4][64];     // [kq][bg][lane]
    __shared__ float sc[64];
    __shared__ float attnS[64][52];      // [b][s] staged attn for P3
    int* flags = bar + 128;  int* go = bar + 192;

    const short* BpQ = W1p + (((size_t)j * 32 + kq * 8) * 64 + lane) * 8;
    const float b1v = b1[u];
    const float dz = db1[u], dr = db1[UU + u], dhh = db1[2 * UU + u];
    const float bV0 = bV[0];

    float Vl[16];
    #pragma unroll
    for (int e = 0; e < 16; e += 4)
        *(float4*)&Vl[e] = *(const float4*)(Vw + lane * 16 + e);

    // P3 thread mapping: b = tid>>4, u16 = tid&15
    const int p_b  = tid >> 4;
    const int p_u  = j * 16 + (tid & 15);
    const short* xgb = xg + (size_t)p_b * G3;
    const float dz3 = db1[p_u], dr3 = db1[UU + p_u], dh3 = db1[2 * UU + p_u];

    for (int t = 0; t < TD; ++t) {
        const short* dh = t ? Hbf + (size_t)(t - 1) * BB * UU
                            : eout + (size_t)(SS - 1) * BB * UU;
        // ---- P1: q slice ----
        {
            const short* Arow = dh + (size_t)(bg * 16 + l15) * UU + kq * 256 + quad * 8;
            f32x4 aq = (f32x4)0.0f;
            #pragma unroll
            for (int i = 0; i < 8; ++i)
                aq = mfma16(vload16(Arow + i * 32), *(const short8*)(BpQ + i * 512), aq);
            redq[kq][bg][lane] = aq;
        }
        __syncthreads();
        if (kq == 0) {
            f32x4 s = redq[0][bg][lane] + redq[1][bg][lane] + redq[2][bg][lane] + redq[3][bg][lane];
            #pragma unroll
            for (int r = 0; r < 4; ++r)
                vstore_bf(q_bf + (size_t)(bg * 16 + quad * 4 + r) * UU + u, s[r] + b1v);
        }
        gbar(flags, go, 3 * t + 1);
        // ---- P2: block = batch b = j: scores + softmax -> attn_g ----
        {
            const int b = j;
            float ql[16];
            {
                short8 q0 = vload16(q_bf + (size_t)b * UU + lane * 16);
                short8 q1 = vload16(q_bf + (size_t)b * UU + lane * 16 + 8);
                #pragma unroll
                for (int e = 0; e < 8; ++e) { ql[e] = bf2f(q0[e]); ql[8 + e] = bf2f(q1[e]); }
            }
            for (int s = wave; s < SS; s += 16) {
                const short* kp = keysb + ((size_t)s * BB + b) * UU + lane * 16;
                short8 k0 = *(const short8*)kp;
                short8 k1 = *(const short8*)(kp + 8);
                float p = 0.0f;
                #pragma unroll
                for (int e = 0; e < 8; ++e) p += Vl[e] * ftanh(ql[e] + bf2f(k0[e]));
                #pragma unroll
                for (int e = 0; e < 8; ++e) p += Vl[8 + e] * ftanh(ql[8 + e] + bf2f(k1[e]));
                #pragma unroll
                for (int off = 32; off; off >>= 1) p += __shfl_down(p, off);
                if (lane == 0) sc[s] = p + bV0;
            }
            __syncthreads();
            if (wave == 0) {
                float v = (lane < SS) ? sc[lane] : -1e30f;
                float m = v;
                #pragma unroll
                for (int off = 32; off; off >>= 1) m = fmaxf(m, __shfl_down(m, off));
                m = __shfl(m, 0);
                float e = (lane < SS) ? __expf(v - m) : 0.0f;
                float ss = e;
                #pragma unroll
                for (int off = 32; off; off >>= 1) ss += __shfl_down(ss, off);
                ss = __shfl(ss, 0);
                if (lane < SS) vstore_f(attn_g + b * 64 + lane, e / ss);
            }
        }
        gbar(flags, go, 3 * t + 2);
        // ---- P3: stage attn -> LDS; gi = sum_s attn*P; GRU(h=0) -> Hbf ----
        {
            // 3200 attn values, 1024 threads
            for (int i = tid; i < BB * SS; i += 1024) {
                int b = i / SS, s = i - b * SS;
                attnS[b][s] = vload_f(attn_g + b * 64 + s);
            }
            __syncthreads();
            float g0 = 0.0f, g1 = 0.0f, g2 = 0.0f;
            const short* Pb = P + (size_t)p_b * G3 + p_u;
            #pragma unroll 2
            for (int s = 0; s < SS; ++s) {
                float w = attnS[p_b][s];
                const short* Pr = Pb + (size_t)s * BB * G3;
                g0 += w * bf2f(Pr[0]);
                g1 += w * bf2f(Pr[UU]);
                g2 += w * bf2f(Pr[2 * UU]);
            }
            const short* xb = xgb + (size_t)t * BB * G3;
            g0 += bf2f(xb[p_u]);
            g1 += bf2f(xb[UU + p_u]);
            g2 += bf2f(xb[2 * UU + p_u]);
            float z  = sigm(g0 + dz3);
            float rr = sigm(g1 + dr3);
            float hc = ftanh(g2 + rr * dh3);
            vstore_bf(Hbf + (size_t)t * BB * UU + (size_t)p_b * UU + p_u, (1.0f - z) * hc);
        }
        if (t != TD - 1) gbar(flags, go, 3 * t + 3);
        else break;
    }
    (void)dz; (void)dr; (void)dhh;
}

// ---------------------------------------------------------------------------
// Loss over one logits chunk.
// ---------------------------------------------------------------------------
__global__ __launch_bounds__(256) void loss_kernel(
    const float* __restrict__ logits, const int* __restrict__ targ,
    int rows0, float* __restrict__ out)
{
    int gr = rows0 + blockIdx.x;
    int t = gr >> 6;
    if (t >= TD) return;
    int b = gr & 63;
    const float* lp = logits + (size_t)blockIdx.x * VT;
    int tid = threadIdx.x;
    __shared__ float redm[4], reds[4];

    float m = -INFINITY;
    for (int v = tid; v < VT; v += 256) m = fmaxf(m, lp[v]);
    #pragma unroll
    for (int off = 32; off; off >>= 1) m = fmaxf(m, __shfl_down(m, off));
    if ((tid & 63) == 0) redm[tid >> 6] = m;
    __syncthreads();
    float mm = fmaxf(fmaxf(redm[0], redm[1]), fmaxf(redm[2], redm[3]));

    float ssum = 0.0f;
    for (int v = tid; v < VT; v += 256) ssum += expf(lp[v] - mm);
    #pragma unroll
    for (int off = 32; off; off >>= 1) ssum += __shfl_down(ssum, off);
    if ((tid & 63) == 0) reds[tid >> 6] = ssum;
    __syncthreads();
    if (tid == 0) {
        float tot = reds[0] + reds[1] + reds[2] + reds[3];
        int y = targ[b * TT + t + 1];
        float nll = mm + logf(tot) - lp[y];
        if (y != 0) atomicAdd(out, nll * (1.0f / (float)BB));
    }
}

// ---------------------------------------------------------------------------
extern "C" void kernel_launch(void* const* d_in, const int* in_sizes, int n_in,
                              void* d_out, int out_size, void* d_ws, size_t ws_size,
                              hipStream_t stream)
{
    (void)in_sizes; (void)n_in; (void)out_size; (void)ws_size;
    const int*   inp      = (const int*)  d_in[0];
    const int*   targ     = (const int*)  d_in[1];
    const float* enc_h0   = (const float*)d_in[2];
    const float* enc_emb  = (const float*)d_in[3];
    const float* enc_Wx   = (const float*)d_in[4];
    const float* enc_Wh   = (const float*)d_in[5];
    const float* enc_b    = (const float*)d_in[6];
    const float* W1       = (const float*)d_in[7];
    const float* b1       = (const float*)d_in[8];
    const float* W2       = (const float*)d_in[9];
    const float* b2       = (const float*)d_in[10];
    const float* Vw       = (const float*)d_in[11];
    const float* bV       = (const float*)d_in[12];
    const float* dec_emb  = (const float*)d_in[13];
    const float* dec_Wx   = (const float*)d_in[14];
    /* dec_Wh (d_in[15]) mathematically unused: decoder GRU gets h==0 */
    const float* dec_b    = (const float*)d_in[16];
    const float* fc_W     = (const float*)d_in[17];
    const float* fc_b     = (const float*)d_in[18];
    float* out = (float*)d_out;

    char* p = (char*)d_ws;
    auto alloc = [&](size_t bytes) {
        char* r = (char*)(((uintptr_t)p + 255) & ~(uintptr_t)255);
        p = r + bytes;
        return r;
    };
    short* encWxt  = (short*)alloc((size_t)G3 * EE * 2);
    short* encWht  = (short*)alloc((size_t)G3 * UU * 2);
    short* W1t     = (short*)alloc((size_t)UU * UU * 2);
    short* W2t     = (short*)alloc((size_t)UU * UU * 2);
    short* dWxt_c  = (short*)alloc((size_t)G3 * UU * 2);
    short* dWxt_e  = (short*)alloc((size_t)G3 * EE * 2);
    short* fcWt    = (short*)alloc((size_t)VT * UU * 2);
    short* encWhp  = (short*)alloc((size_t)G3 * UU * 2);   // fragment-packed
    short* W1p     = (short*)alloc((size_t)UU * UU * 2);
    short* Ae      = (short*)alloc((size_t)MPAD * EE * 2);
    short* Ad      = (short*)alloc((size_t)MPAD * EE * 2);
    short* enc_gi  = (short*)alloc((size_t)MPAD * G3 * 2);
    short* xemb_gi = (short*)alloc((size_t)MPAD * G3 * 2);
    short* enc_out = (short*)alloc((size_t)MPAD * UU * 2);
    short* keysb   = (short*)alloc((size_t)MPAD * UU * 2);
    short* Pmat    = (short*)alloc((size_t)MPAD * G3 * 2);  // eout @ dWx_ctx
    short* H_bf    = (short*)alloc((size_t)MPAD * UU * 2);
    short* h0_bf   = (short*)alloc((size_t)BB * UU * 2);
    short* q_bf    = (short*)alloc((size_t)BB * UU * 2);
    float* attn_g  = (float*)alloc((size_t)BB * 64 * 4);
    float* logits  = (float*)alloc((size_t)256 * VT * 4);
    int*   bar     = (int*)alloc(256 * 4);

    // --- one-time prep (parallel) ---
    transpose_bf<<<dim3(G3/64, EE/64), 256, 0, stream>>>(enc_Wx, encWxt, G3, EE);
    transpose_bf<<<dim3(G3/64, UU/64), 256, 0, stream>>>(enc_Wh, encWht, G3, UU);
    transpose_bf<<<dim3(UU/64, UU/64), 256, 0, stream>>>(W1, W1t, UU, UU);
    transpose_bf<<<dim3(UU/64, UU/64), 256, 0, stream>>>(W2, W2t, UU, UU);
    transpose_bf<<<dim3(G3/64, UU/64), 256, 0, stream>>>(dec_Wx, dWxt_c, G3, UU);
    transpose_bf<<<dim3(G3/64, EE/64), 256, 0, stream>>>(dec_Wx + (size_t)UU * G3, dWxt_e, G3, EE);
    transpose_bf<<<dim3(VT/64, UU/64), 256, 0, stream>>>(fc_W, fcWt, VT, UU);
    pack_frag<<<dim3(8, G3/16), 256, 0, stream>>>(encWht, encWhp, UU);
    pack_frag<<<dim3(8, UU/16), 256, 0, stream>>>(W1t, W1p, UU);
    prep_gather<<<2 * MPAD + 64, 256, 0, stream>>>(inp, targ, enc_emb, dec_emb, enc_h0,
                                                   Ae, Ad, H_bf, h0_bf, out, bar);

    gemm_bf16<128,128,64,64,true><<<dim3(G3/128, MPAD/128), 256, 0, stream>>>(
        Ae, encWxt, enc_b, enc_gi, G3, EE, EE, EE);
    gemm_bf16<128,128,64,64,true><<<dim3(G3/128, MPAD/128), 256, 0, stream>>>(
        Ad, dWxt_e, dec_b, xemb_gi, G3, EE, EE, EE);

    // --- encoder persistent scan (cooperative launch for co-residency) ---
    {
        const short* a0 = h0_bf; const short* a1 = encWhp; const short* a2 = enc_gi;
        const float* a3 = enc_b + G3; short* a4 = enc_out; int* a5 = bar;
        void* args[] = {&a0, &a1, &a2, &a3, &a4, &a5};
        hipLaunchCooperativeKernel((void*)enc_scan, dim3(64), dim3(1024), args, 0, stream);
    }

    // keys = enc_out @ W2 + b2  (bf16);  P = eout @ dWx_ctx  (bf16)
    gemm_bf16<128,128,64,64,true><<<dim3(UU/128, MPAD/128), 256, 0, stream>>>(
        enc_out, W2t, b2, keysb, UU, UU, UU, UU);
    gemm_bf16<128,128,64,64,true><<<dim3(G3/128, MPAD/128), 256, 0, stream>>>(
        enc_out, dWxt_c, nullptr, Pmat, G3, UU, UU, UU);

    // --- decoder persistent scan (cooperative) ---
    {
        const short* a0 = enc_out; const short* a1 = W1p; const float* a2 = b1;
        const short* a3 = keysb; const float* a4 = Vw; const float* a5 = bV;
        const short* a6 = Pmat; const short* a7 = xemb_gi; const float* a8 = dec_b + G3;
        short* a9 = q_bf; float* a10 = attn_g; short* a11 = H_bf; int* a12 = bar;
        void* args[] = {&a0, &a1, &a2, &a3, &a4, &a5, &a6, &a7, &a8, &a9, &a10, &a11, &a12};
        hipLaunchCooperativeKernel((void*)dec_scan, dim3(64), dim3(1024), args, 0, stream);
    }

    // --- fc + loss, chunks of 256 rows ---
    for (int rows0 = 0; rows0 < MPAD; rows0 += 256) {
        int rows = MPAD - rows0; if (rows > 256) rows = 256;
        gemm_bf16<128,128,64,64,false><<<dim3(VT/128, rows/128), 256, 0, stream>>>(
            H_bf + (size_t)rows0 * UU, fcWt, fc_b, logits, VT, UU, UU, UU);
        loss_kernel<<<rows, 256, 0, stream>>>(logits, targ, rows0, out);
    }
}

// Round 6
// 2711.350 us; speedup vs baseline: 8.2592x; 1.4093x over previous
//
#include <hip/hip_runtime.h>
#include <cstdint>
#include <cstddef>

#define BB 64      // batch
#define SS 50      // src len
#define TT 50      // tgt len
#define TD 49      // decoder steps
#define UU 1024    // hidden
#define EE 256     // embed
#define VT 16000   // tgt vocab
#define G3 3072    // 3*U
#define MPAD 3200  // 50*64 padded row count

using short8 = __attribute__((ext_vector_type(8))) short;
using short4v = __attribute__((ext_vector_type(4))) short;
using uint4v = __attribute__((ext_vector_type(4))) unsigned int;
using f32x4  = __attribute__((ext_vector_type(4))) float;

__device__ __forceinline__ short f2bf(float f) {
    uint32_t u = __float_as_uint(f);
    uint32_t r = (u + 0x7fffu + ((u >> 16) & 1u)) >> 16;
    return (short)r;
}
__device__ __forceinline__ float bf2f(short s) {
    return __uint_as_float(((uint32_t)(uint16_t)s) << 16);
}
__device__ __forceinline__ float sigm(float x) { return 1.0f / (1.0f + __expf(-x)); }
__device__ __forceinline__ float ftanh(float x) {
    float xc = fminf(fmaxf(x, -8.0f), 8.0f);
    float e = __expf(2.0f * xc);
    return (e - 1.0f) / (e + 1.0f);
}

// ---- cache-bypassing accesses for data written by other blocks in-kernel ----
__device__ __forceinline__ short8 vload16(const short* p) {
    union { uint4v u; short8 s; } c;
    c.u = *(const volatile uint4v*)p;
    return c.s;
}
__device__ __forceinline__ float vload_bf(const short* p) { return bf2f(*(const volatile short*)p); }
__device__ __forceinline__ void vstore_bf(short* p, float v) { *(volatile short*)p = f2bf(v); }

// Contention-free grid barrier: per-block arrival flags (plain relaxed stores,
// no RMW), leader block ballot-polls all 64 flags, releases via `go` word.
__device__ __forceinline__ void gbar(int* flags, int* go, int t) {
    asm volatile("s_waitcnt vmcnt(0)" ::: "memory");   // my data stores drained
    __syncthreads();
    if (blockIdx.x == 0) {
        if (threadIdx.x < 64) {
            if (threadIdx.x == 0)
                __hip_atomic_store(&flags[0], t, __ATOMIC_RELAXED, __HIP_MEMORY_SCOPE_AGENT);
            int v;
            do {
                v = __hip_atomic_load(&flags[threadIdx.x], __ATOMIC_RELAXED, __HIP_MEMORY_SCOPE_AGENT);
            } while (__ballot(v >= t) != ~0ull);
            if (threadIdx.x == 0)
                __hip_atomic_store(go, t, __ATOMIC_RELAXED, __HIP_MEMORY_SCOPE_AGENT);
        }
    } else {
        if (threadIdx.x == 0) {
            __hip_atomic_store(&flags[blockIdx.x], t, __ATOMIC_RELAXED, __HIP_MEMORY_SCOPE_AGENT);
            while (__hip_atomic_load(go, __ATOMIC_RELAXED, __HIP_MEMORY_SCOPE_AGENT) < t)
                __builtin_amdgcn_s_sleep(1);
        }
    }
    __syncthreads();
}

typedef __attribute__((address_space(3))) void lds_vp;
typedef __attribute__((address_space(1))) void gl_vp;
__device__ __forceinline__ void gload16(void* lds, const void* g) {
    __builtin_amdgcn_global_load_lds((const gl_vp*)(uintptr_t)g,
                                     (lds_vp*)(uint32_t)(uintptr_t)lds,
                                     16, 0, 0);
}
__device__ __forceinline__ f32x4 mfma16(short8 a, short8 b, f32x4 c) {
    return __builtin_amdgcn_mfma_f32_16x16x32_bf16(a, b, c, 0, 0, 0);
}

// ---------------------------------------------------------------------------
// bf16 MFMA GEMM: C[m][n] = sum_k A[m][k]*Bt[n][k] (+bias)
// REMAP 0: row-major [M][N].
// REMAP 1: rows m=s*64+b remapped to [b][s][N]   (keys layout)
// REMAP 2: [b][s][u][gate-pad4]                  (P layout, N=3072)
// ---------------------------------------------------------------------------
template<int BM, int BN, int WM, int WN, bool OUT_BF16, int REMAP>
__global__ __launch_bounds__(256) void gemm_bf16(
    const short* __restrict__ A, const short* __restrict__ Bt,
    const float* __restrict__ bias, void* __restrict__ C, int N, int K,
    int lda, int ldb)
{
    constexpr int BK = 32;
    __shared__ __attribute__((aligned(16))) short As[BM * BK];
    __shared__ __attribute__((aligned(16))) short Bs[BN * BK];

    const int tid  = threadIdx.x;
    const int wave = tid >> 6;
    const int lane = tid & 63;
    const int l15  = lane & 15;
    const int quad = lane >> 4;
    const int wm = wave >> 1, wn = wave & 1;
    const int n0 = blockIdx.x * BN;
    const int m0 = blockIdx.y * BM;

    f32x4 acc[WM / 16][WN / 16];
    #pragma unroll
    for (int i = 0; i < WM / 16; ++i)
        #pragma unroll
        for (int j = 0; j < WN / 16; ++j)
            acc[i][j] = (f32x4)0.0f;

    for (int k0 = 0; k0 < K; k0 += BK) {
        #pragma unroll
        for (int it = 0; it < BM / 64; ++it) {
            int e = (it * 256 + tid) * 8;
            int row = e >> 5, col = e & 31;
            gload16(As + (it * 256 + wave * 64) * 8,
                    A + (size_t)(m0 + row) * lda + k0 + col);
        }
        #pragma unroll
        for (int it = 0; it < BN / 64; ++it) {
            int e = (it * 256 + tid) * 8;
            int row = e >> 5, col = e & 31;
            gload16(Bs + (it * 256 + wave * 64) * 8,
                    Bt + (size_t)(n0 + row) * ldb + k0 + col);
        }
        __syncthreads();
        short8 af[WM / 16], bfr[WN / 16];
        #pragma unroll
        for (int i = 0; i < WM / 16; ++i)
            af[i] = *(const short8*)(As + (wm * WM + i * 16 + l15) * BK + quad * 8);
        #pragma unroll
        for (int j = 0; j < WN / 16; ++j)
            bfr[j] = *(const short8*)(Bs + (wn * WN + j * 16 + l15) * BK + quad * 8);
        #pragma unroll
        for (int i = 0; i < WM / 16; ++i)
            #pragma unroll
            for (int j = 0; j < WN / 16; ++j)
                acc[i][j] = mfma16(af[i], bfr[j], acc[i][j]);
        __syncthreads();
    }

    #pragma unroll
    for (int i = 0; i < WM / 16; ++i) {
        #pragma unroll
        for (int j = 0; j < WN / 16; ++j) {
            int row = m0 + wm * WM + i * 16 + quad * 4;
            int col = n0 + wn * WN + j * 16 + l15;
            float bia = bias ? bias[col] : 0.0f;
            #pragma unroll
            for (int r = 0; r < 4; ++r) {
                size_t off;
                if (REMAP == 1)
                    off = ((size_t)((row + r) & 63) * SS + ((row + r) >> 6)) * N + col;
                else if (REMAP == 2)
                    off = (((size_t)((row + r) & 63) * SS + ((row + r) >> 6)) * UU
                           + (col & 1023)) * 4 + (col >> 10);
                else
                    off = (size_t)(row + r) * N + col;
                float v = acc[i][j][r] + bia;
                if (OUT_BF16) ((short*)C)[off] = f2bf(v);
                else          ((float*)C)[off] = v;
            }
        }
    }
}

// ---------------------------------------------------------------------------
// Transpose fp32 [K][N] -> bf16 [N][K]
// ---------------------------------------------------------------------------
__global__ __launch_bounds__(256) void transpose_bf(
    const float* __restrict__ in, short* __restrict__ out, int ldin, int ldout)
{
    __shared__ float tile[64][65];
    int n0 = blockIdx.x * 64, k0 = blockIdx.y * 64;
    int c = threadIdx.x & 63, rr = threadIdx.x >> 6;
    #pragma unroll 4
    for (int i = 0; i < 16; ++i) {
        int row = rr * 16 + i;
        tile[row][c] = in[(size_t)(k0 + row) * ldin + n0 + c];
    }
    __syncthreads();
    #pragma unroll 4
    for (int i = 0; i < 16; ++i) {
        int row = rr * 16 + i;
        out[(size_t)(n0 + row) * ldout + k0 + c] = f2bf(tile[c][row]);
    }
}

// ---------------------------------------------------------------------------
// Fused transpose + MFMA-fragment pack: fp32 W[K][N] -> packed bf16
// Wp[((nt*(K/32)+it)*64+lane)*8+e] = bf16(W[it*32+(lane>>4)*8+e][nt*16+(lane&15)])
// Grid ((K/32)/4, N/16), 256 threads.
// ---------------------------------------------------------------------------
__global__ __launch_bounds__(256) void transpose_pack(
    const float* __restrict__ W, short* __restrict__ Wp, int N, int K)
{
    int lane = threadIdx.x & 63;
    int it = blockIdx.x * 4 + (threadIdx.x >> 6);
    int nt = blockIdx.y;
    int KI = K >> 5;
    int kb = it * 32 + (lane >> 4) * 8;
    int n  = nt * 16 + (lane & 15);
    short8 v;
    #pragma unroll
    for (int e = 0; e < 8; ++e)
        v[e] = f2bf(W[(size_t)(kb + e) * N + n]);
    *(short8*)(Wp + (((size_t)nt * KI + it) * 64 + lane) * 8) = v;
}

// ---------------------------------------------------------------------------
// Prep: gather embeddings, convert h0, zero pads/out/barriers.
// ---------------------------------------------------------------------------
__global__ __launch_bounds__(256) void prep_gather(
    const int* __restrict__ inp, const int* __restrict__ targ,
    const float* __restrict__ enc_emb, const float* __restrict__ dec_emb,
    const float* __restrict__ enc_h0,
    short* __restrict__ Ae, short* __restrict__ Ad,
    short* __restrict__ H_bf, short* __restrict__ h0_bf,
    float* __restrict__ out, int* __restrict__ bar)
{
    int blk = blockIdx.x, tid = threadIdx.x;
    if (blk < MPAD) {
        int s = blk >> 6, b = blk & 63;
        int row = inp[b * SS + s];
        Ae[(size_t)blk * EE + tid] = f2bf(enc_emb[(size_t)row * EE + tid]);
    } else if (blk < 2 * MPAD) {
        int m = blk - MPAD;
        if (m < TD * BB) {
            int t = m >> 6, b = m & 63;
            int row = targ[b * TT + t];
            Ad[(size_t)m * EE + tid] = f2bf(dec_emb[(size_t)row * EE + tid]);
        } else {
            Ad[(size_t)m * EE + tid] = 0;
        }
    } else {
        int r = blk - 2 * MPAD;  // 0..63
        for (int u = tid; u < UU; u += 256) {
            H_bf[(size_t)(TD * BB + r) * UU + u] = 0;   // fc pad rows
            h0_bf[(size_t)r * UU + u] = f2bf(enc_h0[(size_t)r * UU + u]);
        }
        if (r == 0) {
            bar[tid] = 0;                                // 256 barrier words
            if (tid == 0) out[0] = 0.0f;
        }
    }
}

// ---------------------------------------------------------------------------
// Encoder persistent scan. 64 blocks x 1024 threads. Block j owns u-cols
// [j*16,(j+1)*16). wave=(bg,kq). Weights L2-resident (fragment-packed).
// ---------------------------------------------------------------------------
__global__ __launch_bounds__(1024) void enc_scan(
    const short* __restrict__ h0, const short* __restrict__ Whp,
    const short* __restrict__ gi, const float* __restrict__ bias2,
    short* __restrict__ eout, int* __restrict__ bar)
{
    const int j    = blockIdx.x;
    const int tid  = threadIdx.x;
    const int lane = tid & 63;
    const int l15  = lane & 15;
    const int quad = lane >> 4;
    const int wave = tid >> 6;
    const int bg   = wave & 3;
    const int kq   = wave >> 2;
    const int u    = j * 16 + l15;

    __shared__ f32x4 red[4][3][4][64];   // [kq][gate][bg][lane]
    int* flags = bar;     int* go = bar + 64;

    const short* Bp0 = Whp + ((((size_t)(0 * 64 + j)) * 32 + kq * 8) * 64 + lane) * 8;
    const short* Bp1 = Whp + ((((size_t)(1 * 64 + j)) * 32 + kq * 8) * 64 + lane) * 8;
    const short* Bp2 = Whp + ((((size_t)(2 * 64 + j)) * 32 + kq * 8) * 64 + lane) * 8;
    const float bz = bias2[u], br = bias2[UU + u], bh = bias2[2 * UU + u];

    for (int t = 0; t < SS; ++t) {
        const short* A = t ? eout + (size_t)(t - 1) * BB * UU : h0;
        const short* Arow = A + (size_t)(bg * 16 + l15) * UU + kq * 256 + quad * 8;
        f32x4 a0 = (f32x4)0.0f, a1 = (f32x4)0.0f, a2 = (f32x4)0.0f;
        #pragma unroll
        for (int i = 0; i < 8; ++i) {
            short8 af = vload16(Arow + i * 32);
            a0 = mfma16(af, *(const short8*)(Bp0 + i * 512), a0);
            a1 = mfma16(af, *(const short8*)(Bp1 + i * 512), a1);
            a2 = mfma16(af, *(const short8*)(Bp2 + i * 512), a2);
        }
        red[kq][0][bg][lane] = a0;
        red[kq][1][bg][lane] = a1;
        red[kq][2][bg][lane] = a2;
        __syncthreads();
        if (kq == 0) {
            f32x4 s0 = red[0][0][bg][lane] + red[1][0][bg][lane] + red[2][0][bg][lane] + red[3][0][bg][lane];
            f32x4 s1 = red[0][1][bg][lane] + red[1][1][bg][lane] + red[2][1][bg][lane] + red[3][1][bg][lane];
            f32x4 s2 = red[0][2][bg][lane] + red[1][2][bg][lane] + red[2][2][bg][lane] + red[3][2][bg][lane];
            const short* git = gi + (size_t)t * BB * G3;
            #pragma unroll
            for (int r = 0; r < 4; ++r) {
                int b = bg * 16 + quad * 4 + r;
                const short* gb = git + (size_t)b * G3;
                float iz = bf2f(gb[u]), ir = bf2f(gb[UU + u]), ih = bf2f(gb[2 * UU + u]);
                float h = vload_bf(A + (size_t)b * UU + u);
                float z  = sigm(iz + s0[r] + bz);
                float rr = sigm(ir + s1[r] + br);
                float hc = ftanh(ih + rr * (s2[r] + bh));
                vstore_bf(eout + (size_t)t * BB * UU + (size_t)b * UU + u,
                          z * h + (1.0f - z) * hc);
            }
        }
        if (t != SS - 1) gbar(flags, go, t + 1);
    }
}

// ---------------------------------------------------------------------------
// Decoder persistent scan. 64 blocks x 1024 threads. 2 phases / 2 barriers:
//  P1 : block j computes q[all b][u-slice j] = dh @ W1 + b1 (k-split waves)
//  P23: block b: scores+softmax (attn in LDS), then
//       gi[u] = sum_s attn[s]*Pp4[b][s][u][:] + xemb, GRU(h=0) -> Hbf[t][b]
// Pp4 = (eout @ dWx_ctx) in [b][s][u][gate-pad4] layout: fully coalesced,
// per-block slice contiguous & cache-resident (ctx GEMM algebraically gone).
// ---------------------------------------------------------------------------
__global__ __launch_bounds__(1024) void dec_scan(
    const short* __restrict__ eout, const short* __restrict__ W1p,
    const float* __restrict__ b1, const short* __restrict__ keyp,
    const float* __restrict__ Vw, const float* __restrict__ bV,
    const short* __restrict__ Pp4, const short* __restrict__ xg,
    const float* __restrict__ db1, short* __restrict__ q_bf,
    short* __restrict__ Hbf, int* __restrict__ bar)
{
    const int j    = blockIdx.x;
    const int tid  = threadIdx.x;
    const int lane = tid & 63;
    const int l15  = lane & 15;
    const int quad = lane >> 4;
    const int wave = tid >> 6;
    const int bg   = wave & 3;
    const int kq   = wave >> 2;
    const int u    = j * 16 + l15;

    __shared__ f32x4 redq[4][4][64];     // [kq][bg][lane]
    __shared__ float sc[64];
    __shared__ float attnw[64];
    int* flags = bar + 128;  int* go = bar + 192;

    const short* BpQ = W1p + (((size_t)j * 32 + kq * 8) * 64 + lane) * 8;
    const float b1v = b1[u];
    const float bV0 = bV[0];

    float Vl[16];
    #pragma unroll
    for (int e = 0; e < 16; e += 4)
        *(float4*)&Vl[e] = *(const float4*)(Vw + lane * 16 + e);

    // P23 per-thread constants (u = tid)
    const float dz3 = db1[tid], dr3 = db1[UU + tid], dh3 = db1[2 * UU + tid];
    const short* Pb = Pp4 + (size_t)j * SS * UU * 4;   // block b = j slice

    for (int t = 0; t < TD; ++t) {
        const short* dh = t ? Hbf + (size_t)(t - 1) * BB * UU
                            : eout + (size_t)(SS - 1) * BB * UU;
        // ---- P1: q slice (block j), k-split over 16 waves ----
        {
            const short* Arow = dh + (size_t)(bg * 16 + l15) * UU + kq * 256 + quad * 8;
            f32x4 aq = (f32x4)0.0f;
            #pragma unroll
            for (int i = 0; i < 8; ++i)
                aq = mfma16(vload16(Arow + i * 32), *(const short8*)(BpQ + i * 512), aq);
            redq[kq][bg][lane] = aq;
        }
        __syncthreads();
        if (kq == 0) {
            f32x4 s = redq[0][bg][lane] + redq[1][bg][lane] + redq[2][bg][lane] + redq[3][bg][lane];
            #pragma unroll
            for (int r = 0; r < 4; ++r)
                vstore_bf(q_bf + (size_t)(bg * 16 + quad * 4 + r) * UU + u, s[r] + b1v);
        }
        gbar(flags, go, 2 * t + 1);
        // ---- P23: block = batch b = j ----
        {
            const int b = j;
            float ql[16];
            {
                short8 q0 = vload16(q_bf + (size_t)b * UU + lane * 16);
                short8 q1 = vload16(q_bf + (size_t)b * UU + lane * 16 + 8);
                #pragma unroll
                for (int e = 0; e < 8; ++e) { ql[e] = bf2f(q0[e]); ql[8 + e] = bf2f(q1[e]); }
            }
            for (int s = wave; s < SS; s += 16) {
                const short* kp = keyp + ((size_t)b * SS + s) * UU + lane * 16;
                short8 k0 = *(const short8*)kp;
                short8 k1 = *(const short8*)(kp + 8);
                float p = 0.0f;
                #pragma unroll
                for (int e = 0; e < 8; ++e) p += Vl[e] * ftanh(ql[e] + bf2f(k0[e]));
                #pragma unroll
                for (int e = 0; e < 8; ++e) p += Vl[8 + e] * ftanh(ql[8 + e] + bf2f(k1[e]));
                #pragma unroll
                for (int off = 32; off; off >>= 1) p += __shfl_down(p, off);
                if (lane == 0) sc[s] = p + bV0;
            }
            __syncthreads();
            if (wave == 0) {
                float v = (lane < SS) ? sc[lane] : -1e30f;
                float m = v;
                #pragma unroll
                for (int off = 32; off; off >>= 1) m = fmaxf(m, __shfl_down(m, off));
                m = __shfl(m, 0);
                float e = (lane < SS) ? __expf(v - m) : 0.0f;
                float ss = e;
                #pragma unroll
                for (int off = 32; off; off >>= 1) ss += __shfl_down(ss, off);
                ss = __shfl(ss, 0);
                if (lane < SS) attnw[lane] = e / ss;
            }
            __syncthreads();
            // gi over contiguous Pp4 slice: one 8B load per s per thread
            float g0 = 0.0f, g1 = 0.0f, g2 = 0.0f;
            const short* Pu = Pb + (size_t)tid * 4;
            #pragma unroll 2
            for (int s = 0; s < SS; ++s) {
                float w = attnw[s];
                short4v pv = *(const short4v*)(Pu + (size_t)s * UU * 4);
                g0 += w * bf2f(pv[0]);
                g1 += w * bf2f(pv[1]);
                g2 += w * bf2f(pv[2]);
            }
            const short* xb = xg + ((size_t)t * BB + b) * G3;
            g0 += bf2f(xb[tid]);
            g1 += bf2f(xb[UU + tid]);
            g2 += bf2f(xb[2 * UU + tid]);
            float z  = sigm(g0 + dz3);
            float rr = sigm(g1 + dr3);
            float hc = ftanh(g2 + rr * dh3);
            vstore_bf(Hbf + ((size_t)t * BB + b) * UU + tid, (1.0f - z) * hc);
        }
        if (t != TD - 1) gbar(flags, go, 2 * t + 2);
    }
}

// ---------------------------------------------------------------------------
// Loss over one logits chunk.
// ---------------------------------------------------------------------------
__global__ __launch_bounds__(256) void loss_kernel(
    const float* __restrict__ logits, const int* __restrict__ targ,
    int rows0, float* __restrict__ out)
{
    int gr = rows0 + blockIdx.x;
    int t = gr >> 6;
    if (t >= TD) return;
    int b = gr & 63;
    const float* lp = logits + (size_t)blockIdx.x * VT;
    int tid = threadIdx.x;
    __shared__ float redm[4], reds[4];

    float m = -INFINITY;
    for (int v = tid; v < VT; v += 256) m = fmaxf(m, lp[v]);
    #pragma unroll
    for (int off = 32; off; off >>= 1) m = fmaxf(m, __shfl_down(m, off));
    if ((tid & 63) == 0) redm[tid >> 6] = m;
    __syncthreads();
    float mm = fmaxf(fmaxf(redm[0], redm[1]), fmaxf(redm[2], redm[3]));

    float ssum = 0.0f;
    for (int v = tid; v < VT; v += 256) ssum += expf(lp[v] - mm);
    #pragma unroll
    for (int off = 32; off; off >>= 1) ssum += __shfl_down(ssum, off);
    if ((tid & 63) == 0) reds[tid >> 6] = ssum;
    __syncthreads();
    if (tid == 0) {
        float tot = reds[0] + reds[1] + reds[2] + reds[3];
        int y = targ[b * TT + t + 1];
        float nll = mm + logf(tot) - lp[y];
        if (y != 0) atomicAdd(out, nll * (1.0f / (float)BB));
    }
}

// ---------------------------------------------------------------------------
extern "C" void kernel_launch(void* const* d_in, const int* in_sizes, int n_in,
                              void* d_out, int out_size, void* d_ws, size_t ws_size,
                              hipStream_t stream)
{
    (void)in_sizes; (void)n_in; (void)out_size;
    const int*   inp      = (const int*)  d_in[0];
    const int*   targ     = (const int*)  d_in[1];
    const float* enc_h0   = (const float*)d_in[2];
    const float* enc_emb  = (const float*)d_in[3];
    const float* enc_Wx   = (const float*)d_in[4];
    const float* enc_Wh   = (const float*)d_in[5];
    const float* enc_b    = (const float*)d_in[6];
    const float* W1       = (const float*)d_in[7];
    const float* b1       = (const float*)d_in[8];
    const float* W2       = (const float*)d_in[9];
    const float* b2       = (const float*)d_in[10];
    const float* Vw       = (const float*)d_in[11];
    const float* bV       = (const float*)d_in[12];
    const float* dec_emb  = (const float*)d_in[13];
    const float* dec_Wx   = (const float*)d_in[14];
    /* dec_Wh (d_in[15]) mathematically unused: decoder GRU gets h==0 */
    const float* dec_b    = (const float*)d_in[16];
    const float* fc_W     = (const float*)d_in[17];
    const float* fc_b     = (const float*)d_in[18];
    float* out = (float*)d_out;

    char* p = (char*)d_ws;
    auto alloc = [&](size_t bytes) {
        char* r = (char*)(((uintptr_t)p + 255) & ~(uintptr_t)255);
        p = r + bytes;
        return r;
    };
    short* encWxt  = (short*)alloc((size_t)G3 * EE * 2);
    short* W2t     = (short*)alloc((size_t)UU * UU * 2);
    short* dWxt_c  = (short*)alloc((size_t)G3 * UU * 2);
    short* dWxt_e  = (short*)alloc((size_t)G3 * EE * 2);
    short* fcWt    = (short*)alloc((size_t)VT * UU * 2);
    short* encWhp  = (short*)alloc((size_t)G3 * UU * 2);   // fragment-packed
    short* W1p     = (short*)alloc((size_t)UU * UU * 2);   // fragment-packed
    short* Ae      = (short*)alloc((size_t)MPAD * EE * 2);
    short* Ad      = (short*)alloc((size_t)MPAD * EE * 2);
    short* enc_gi  = (short*)alloc((size_t)MPAD * G3 * 2);
    short* xemb_gi = (short*)alloc((size_t)MPAD * G3 * 2);
    short* enc_out = (short*)alloc((size_t)MPAD * UU * 2);
    short* keyp    = (short*)alloc((size_t)MPAD * UU * 2);     // [b][s][u]
    short* Pp4     = (short*)alloc((size_t)MPAD * UU * 4 * 2); // [b][s][u][4]
    short* H_bf    = (short*)alloc((size_t)MPAD * UU * 2);
    short* h0_bf   = (short*)alloc((size_t)BB * UU * 2);
    short* q_bf    = (short*)alloc((size_t)BB * UU * 2);
    int*   bar     = (int*)alloc(256 * 4);

    // fc logits chunk: as large as the remaining workspace allows (<=640 rows)
    size_t used = (size_t)(p - (char*)d_ws);
    size_t avail = (ws_size > used) ? ws_size - used : 0;
    int chunkRows = 640;
    while (chunkRows > 128 && (size_t)chunkRows * VT * 4 + 4096 > avail) chunkRows -= 128;
    float* logits = (float*)alloc((size_t)chunkRows * VT * 4);

    // --- one-time prep (parallel) ---
    transpose_bf<<<dim3(G3/64, EE/64), 256, 0, stream>>>(enc_Wx, encWxt, G3, EE);
    transpose_bf<<<dim3(UU/64, UU/64), 256, 0, stream>>>(W2, W2t, UU, UU);
    transpose_bf<<<dim3(G3/64, UU/64), 256, 0, stream>>>(dec_Wx, dWxt_c, G3, UU);
    transpose_bf<<<dim3(G3/64, EE/64), 256, 0, stream>>>(dec_Wx + (size_t)UU * G3, dWxt_e, G3, EE);
    transpose_bf<<<dim3(VT/64, UU/64), 256, 0, stream>>>(fc_W, fcWt, VT, UU);
    transpose_pack<<<dim3(8, G3/16), 256, 0, stream>>>(enc_Wh, encWhp, G3, UU);
    transpose_pack<<<dim3(8, UU/16), 256, 0, stream>>>(W1, W1p, UU, UU);
    prep_gather<<<2 * MPAD + 64, 256, 0, stream>>>(inp, targ, enc_emb, dec_emb, enc_h0,
                                                   Ae, Ad, H_bf, h0_bf, out, bar);

    gemm_bf16<128,128,64,64,true,0><<<dim3(G3/128, MPAD/128), 256, 0, stream>>>(
        Ae, encWxt, enc_b, enc_gi, G3, EE, EE, EE);
    gemm_bf16<128,128,64,64,true,0><<<dim3(G3/128, MPAD/128), 256, 0, stream>>>(
        Ad, dWxt_e, dec_b, xemb_gi, G3, EE, EE, EE);

    // --- encoder persistent scan (cooperative launch for co-residency) ---
    {
        const short* a0 = h0_bf; const short* a1 = encWhp; const short* a2 = enc_gi;
        const float* a3 = enc_b + G3; short* a4 = enc_out; int* a5 = bar;
        void* args[] = {&a0, &a1, &a2, &a3, &a4, &a5};
        hipLaunchCooperativeKernel((void*)enc_scan, dim3(64), dim3(1024), args, 0, stream);
    }

    // keys -> [b][s][u];  P = eout @ dWx_ctx -> [b][s][u][gate-pad4]
    gemm_bf16<128,128,64,64,true,1><<<dim3(UU/128, MPAD/128), 256, 0, stream>>>(
        enc_out, W2t, b2, keyp, UU, UU, UU, UU);
    gemm_bf16<128,128,64,64,true,2><<<dim3(G3/128, MPAD/128), 256, 0, stream>>>(
        enc_out, dWxt_c, nullptr, Pp4, G3, UU, UU, UU);

    // --- decoder persistent scan (cooperative) ---
    {
        const short* a0 = enc_out; const short* a1 = W1p; const float* a2 = b1;
        const short* a3 = keyp; const float* a4 = Vw; const float* a5 = bV;
        const short* a6 = Pp4; const short* a7 = xemb_gi; const float* a8 = dec_b + G3;
        short* a9 = q_bf; short* a10 = H_bf; int* a11 = bar;
        void* args[] = {&a0, &a1, &a2, &a3, &a4, &a5, &a6, &a7, &a8, &a9, &a10, &a11};
        hipLaunchCooperativeKernel((void*)dec_scan, dim3(64), dim3(1024), args, 0, stream);
    }

    // --- fc + loss, dynamic chunks ---
    for (int rows0 = 0; rows0 < MPAD; rows0 += chunkRows) {
        int rows = MPAD - rows0; if (rows > chunkRows) rows = chunkRows;
        gemm_bf16<128,128,64,64,false,0><<<dim3(VT/128, rows/128), 256, 0, stream>>>(
            H_bf + (size_t)rows0 * UU, fcWt, fc_b, logits, VT, UU, UU, UU);
        loss_kernel<<<rows, 256, 0, stream>>>(logits, targ, rows0, out);
    }
}